// Round 9
// baseline (447.978 us; speedup 1.0000x reference)
//
#include <hip/hip_runtime.h>
#include <hip/hip_fp16.h>
#include <math.h>

#define N_NODES 50000
#define N_EDGES 800000
#define E_TOT   (N_EDGES + N_NODES)
#define EB      ((E_TOT + 255) / 256)   /* 3321 edge blocks in prep */
#define HEADS   4
#define NEG_SLOPE 0.2f
#define SBLK    ((N_NODES + 255) / 256)  /* 196 scan blocks */
#define FBLK    (N_NODES / 16)           /* 3125 fused blocks (exact) */

typedef unsigned int u32;
typedef unsigned short u16;
typedef __attribute__((ext_vector_type(8))) _Float16 f16x8;
typedef __attribute__((ext_vector_type(4))) float f32x4;

// =====================================================================
// DUAL-FORM GAT (r15): aggregate PRE-transform features, GEMM FUSED.
// r15: agg->GEMM HBM round-trip deleted. agg1 wrote 102.8MB + gemm1
// re-read it (51.4MB x2 for layer 2) = ~308MB intermediate traffic.
// Now a block of 4 waves aggregates 16 nodes into a 16xK fp16 LDS tile
// (bit-identical values to the old HBM tile), barriers once, and runs
// the same MFMA fragment math as gemm_mean with A from LDS (row pad +8
// halves -> 2-way bank alias = free) and B streamed from the 0.26MB
// L2-resident weight panel. 8-edge unroll reverted to 4 (R8: 72->74.5us,
// agg is service-bound not ILP-bound).
// =====================================================================

// ---------------- prep: degree count (+epos) + W permute-casts + w~ ---------

__global__ __launch_bounds__(256) void prep(const int* __restrict__ ei,
                                            int* __restrict__ deg,
                                            int* __restrict__ epos,
                                            const float* __restrict__ W1,
                                            __half* __restrict__ B1,
                                            const float* __restrict__ W2,
                                            __half* __restrict__ B2,
                                            const float* __restrict__ att_s1,
                                            const float* __restrict__ att_d1,
                                            const float* __restrict__ att_s2,
                                            const float* __restrict__ att_d2,
                                            float* __restrict__ ws1,
                                            float* __restrict__ wd1,
                                            float* __restrict__ ws2,
                                            float* __restrict__ wd2) {
  int b = blockIdx.x, tid = threadIdx.x;
  if (b < EB) {
    int e = b * 256 + tid;
    if (e < E_TOT) {
      int dst = (e < N_EDGES) ? ei[N_EDGES + e] : (e - N_EDGES);
      epos[e] = atomicAdd(&deg[dst], 1);
    }
    return;
  }
  if (b < EB + 128) {
    // W1[512x256] -> B1'[j=0..127][k=h*256+c]: B1'[j][h*256+c] = W1[h*128+j][c]
    int k4 = (b - EB) * 256 + tid;                 // 32768 float4
    float4 v = ((const float4*)W1)[k4];
    __half2 h01 = __float22half2_rn(make_float2(v.x, v.y));
    __half2 h23 = __float22half2_rn(make_float2(v.z, v.w));
    uint2 pk = make_uint2(*(u32*)&h01, *(u32*)&h23);
    int r = k4 >> 6, h = r >> 7, j = r & 127;      // r = W1 row, 4 elems/chunk
    ((uint2*)B1)[j * 256 + h * 64 + (k4 & 63)] = pk;
    return;
  }
  if (b < EB + 192) {
    // W2[512x128] -> B2'[j][h*128+c] = W2[h*128+j][c]
    int k4 = (b - EB - 128) * 256 + tid;           // 16384 float4
    float4 v = ((const float4*)W2)[k4];
    __half2 h01 = __float22half2_rn(make_float2(v.x, v.y));
    __half2 h23 = __float22half2_rn(make_float2(v.z, v.w));
    uint2 pk = make_uint2(*(u32*)&h01, *(u32*)&h23);
    int r = k4 >> 5, h = r >> 7, j = r & 127;
    ((uint2*)B2)[j * 128 + h * 32 + (k4 & 31)] = pk;
    return;
  }
  // w~ vectors: w~[h][k] = sum_c att[h][c] * W[h*128+c][k]
  int bw = b - (EB + 192);                         // 0..15
  int h = bw & 3;
  if (bw < 8) {
    const float* att = (bw < 4) ? att_s1 : att_d1;
    float* o = (bw < 4) ? ws1 : wd1;
    int k = tid;                                   // 0..255
    float acc = 0.f;
    for (int c = 0; c < 128; ++c)
      acc = fmaf(att[h * 128 + c], W1[(size_t)(h * 128 + c) * 256 + k], acc);
    o[h * 256 + k] = acc;
  } else {
    const float* att = (bw < 12) ? att_s2 : att_d2;
    float* o = (bw < 12) ? ws2 : wd2;
    if (tid < 128) {
      int k = tid;
      float acc = 0.f;
      for (int c = 0; c < 128; ++c)
        acc = fmaf(att[h * 128 + c], W2[(size_t)(h * 128 + c) * 128 + k], acc);
      o[h * 128 + k] = acc;
    }
  }
}

// ---------------- device-wide degree scan (3 tiny launches) ----------------

__global__ __launch_bounds__(256) void scan_blocks(const int* __restrict__ deg,
                                                   int* __restrict__ row_ptr,
                                                   int* __restrict__ bsum) {
  __shared__ int sh[256];
  int tid = threadIdx.x;
  int idx = blockIdx.x * 256 + tid;
  int v = (idx < N_NODES) ? deg[idx] : 0;
  sh[tid] = v;
  __syncthreads();
#pragma unroll
  for (int off = 1; off < 256; off <<= 1) {
    int t = (tid >= off) ? sh[tid - off] : 0;
    __syncthreads();
    sh[tid] += t;
    __syncthreads();
  }
  if (idx < N_NODES) row_ptr[idx + 1] = sh[tid];
  if (tid == 255) bsum[blockIdx.x] = sh[255];
}

__global__ __launch_bounds__(256) void scan_tops(int* __restrict__ bsum) {
  __shared__ int sh[256];
  int tid = threadIdx.x;
  int v = (tid < SBLK) ? bsum[tid] : 0;
  sh[tid] = v;
  __syncthreads();
#pragma unroll
  for (int off = 1; off < 256; off <<= 1) {
    int t = (tid >= off) ? sh[tid - off] : 0;
    __syncthreads();
    sh[tid] += t;
    __syncthreads();
  }
  if (tid < SBLK) bsum[tid] = sh[tid] - v;   // exclusive
}

__global__ __launch_bounds__(256) void scan_add(const int* __restrict__ bsum,
                                                int* __restrict__ row_ptr) {
  int idx = blockIdx.x * 256 + threadIdx.x;
  int off = bsum[blockIdx.x];
  if (idx < N_NODES) row_ptr[idx + 1] += off;
  if (idx == 0) row_ptr[0] = 0;
}

__device__ __forceinline__ float leaky_exp(float a) {
  a = (a >= 0.f) ? a : NEG_SLOPE * a;
  return __expf(a);
}

// ---------------- scatter: no atomics, one packed 8B write per edge --------

__global__ __launch_bounds__(256) void scatter_pos(const int* __restrict__ ei,
                                                   const int* __restrict__ epos,
                                                   const int* __restrict__ row_ptr,
                                                   int2* __restrict__ col2) {
  int e = blockIdx.x * 256 + threadIdx.x;
  if (e >= E_TOT) return;
  int src, dst;
  if (e < N_EDGES) { src = ei[e]; dst = ei[N_EDGES + e]; }
  else             { src = e - N_EDGES; dst = src; }
  int slot = row_ptr[dst] + epos[e];
  col2[slot] = make_int2(src, dst);
}

// ---------------- edge weights in CSR-slot order (both layers) -------------

__global__ __launch_bounds__(256) void edge_weights(const int2* __restrict__ col2,
                                                    const float* __restrict__ as_,
                                                    const float* __restrict__ ad_,
                                                    float4* __restrict__ wtab) {
  int i = blockIdx.x * 256 + threadIdx.x;
  if (i >= E_TOT) return;
  int2 sd = col2[i];
  float4 a = ((const float4*)as_)[sd.x];
  float4 d = ((const float4*)ad_)[sd.y];
  float4 w;
  w.x = leaky_exp(a.x + d.x);
  w.y = leaky_exp(a.y + d.y);
  w.z = leaky_exp(a.z + d.z);
  w.w = leaky_exp(a.w + d.w);
  wtab[i] = w;
}

// ---------------- prep_x: x fp32->fp16 cast + layer-1 scores ----------------

__global__ __launch_bounds__(256) void prep_x(const float* __restrict__ x,
                                              const float* __restrict__ ws1,
                                              const float* __restrict__ wd1,
                                              __half* __restrict__ x16,
                                              float* __restrict__ as_,
                                              float* __restrict__ ad_) {
  int node = (blockIdx.x * 256 + threadIdx.x) >> 6;
  if (node >= N_NODES) return;
  int lane = threadIdx.x & 63;
  int c4 = lane * 4;
  f32x4 xv = *(const f32x4*)(x + (size_t)node * 256 + c4);
  __half2 h01 = __float22half2_rn(make_float2(xv[0], xv[1]));
  __half2 h23 = __float22half2_rn(make_float2(xv[2], xv[3]));
  uint2 pk = make_uint2(*(u32*)&h01, *(u32*)&h23);
  *(uint2*)(x16 + (size_t)node * 256 + c4) = pk;
  float p[8];
#pragma unroll
  for (int v = 0; v < 4; ++v) {
    f32x4 w = *(const f32x4*)(ws1 + v * 256 + c4);
    p[v] = xv[0] * w[0] + xv[1] * w[1] + xv[2] * w[2] + xv[3] * w[3];
    f32x4 u = *(const f32x4*)(wd1 + v * 256 + c4);
    p[4 + v] = xv[0] * u[0] + xv[1] * u[1] + xv[2] * u[2] + xv[3] * u[3];
  }
#pragma unroll
  for (int k = 0; k < 8; ++k)
#pragma unroll
    for (int m = 1; m < 64; m <<= 1)
      p[k] += __shfl_xor(p[k], m, 64);
  if (lane == 0) {
    *(float4*)(as_ + (size_t)node * 4) = make_float4(p[0], p[1], p[2], p[3]);
    *(float4*)(ad_ + (size_t)node * 4) = make_float4(p[4], p[5], p[6], p[7]);
  }
}

// ---------------- score2: layer-2 scores from h (128 ch fp16) ---------------

__global__ __launch_bounds__(256) void score2(const __half* __restrict__ hrow,
                                              const float* __restrict__ ws2,
                                              const float* __restrict__ wd2,
                                              float* __restrict__ as_,
                                              float* __restrict__ ad_) {
  int node = (blockIdx.x * 256 + threadIdx.x) >> 6;
  if (node >= N_NODES) return;
  int lane = threadIdx.x & 63, c = lane * 2;
  float2 f = __half22float2(*(const __half2*)(hrow + (size_t)node * 128 + c));
  float p[8];
#pragma unroll
  for (int v = 0; v < 4; ++v) {
    float2 w = *(const float2*)(ws2 + v * 128 + c);
    p[v] = f.x * w.x + f.y * w.y;
    float2 u = *(const float2*)(wd2 + v * 128 + c);
    p[4 + v] = f.x * u.x + f.y * u.y;
  }
#pragma unroll
  for (int k = 0; k < 8; ++k)
#pragma unroll
    for (int m = 1; m < 64; m <<= 1)
      p[k] += __shfl_xor(p[k], m, 64);
  if (lane == 0) {
    *(float4*)(as_ + (size_t)node * 4) = make_float4(p[0], p[1], p[2], p[3]);
    *(float4*)(ad_ + (size_t)node * 4) = make_float4(p[4], p[5], p[6], p[7]);
  }
}

// ---------------- FUSED aggregate + GEMM ----------------------------------
// Block = 4 waves, 16 nodes. Phase 1: wave w aggregates nodes base+4w..+3
// into a 16 x K fp16 LDS tile (K = HEADS*CHIN, head-concat; values bitwise
// identical to the old HBM agg buffer). Phase 2 (after one barrier):
// out[16x128] = 0.25 * A_lds @ Bm^T + bias via mfma_16x16x32_f16; A from
// LDS (row pad +8 halves: 2-way bank alias only), B 16B/lane from the
// L2-resident weight panel. C/D layout: col=lane&15 (N), row=quad*4+reg (M).

template <int CPL, bool HALF_OUT>   // CPL=4: CHIN=256,K=1024 | CPL=2: CHIN=128,K=512
__global__ __launch_bounds__(256) void gat_fused(
    const __half* __restrict__ tbl, const float4* __restrict__ wtab,
    const int* __restrict__ row_ptr, const int2* __restrict__ col2,
    const __half* __restrict__ Bm, const float* __restrict__ bias,
    void* __restrict__ outv) {
  constexpr int CHIN = CPL * 64;
  constexpr int K = 4 * CHIN;
  constexpr int RST = K + 8;            // padded LDS row stride (halves)
  __shared__ u16 sA[16 * RST];          // 33.0 KB / 16.6 KB
  const int tid = threadIdx.x, lane = tid & 63, wave = tid >> 6;
  const int base = blockIdx.x * 16;
  const int cb = lane * CPL;
  const __half* tb = tbl + cb;
  const int* colx = (const int*)col2;   // .x at index 2*i

  // ---- phase 1: aggregation (4 nodes per wave, sequential) ----
  for (int nn = 0; nn < 4; ++nn) {
    const int row = wave * 4 + nn;
    const int node = base + row;
    int s = __builtin_amdgcn_readfirstlane(row_ptr[node]);
    int e = __builtin_amdgcn_readfirstlane(row_ptr[node + 1]);

    float acc[4][CPL];
#pragma unroll
    for (int h = 0; h < 4; ++h)
#pragma unroll
      for (int c = 0; c < CPL; ++c) acc[h][c] = 0.f;
    float den[4] = {0.f, 0.f, 0.f, 0.f};

    auto accum = [&](uint2 q, float4 w) {
      float wv[4] = {w.x, w.y, w.z, w.w};
#pragma unroll
      for (int h = 0; h < 4; ++h) den[h] += wv[h];
      float f[CPL];
      float2 f0 = __half22float2(*(__half2*)&q.x);
      f[0] = f0.x; f[1] = f0.y;
      if (CPL == 4) {
        float2 f1 = __half22float2(*(__half2*)&q.y);
        f[2] = f1.x; f[3] = f1.y;
      }
#pragma unroll
      for (int h = 0; h < 4; ++h)
#pragma unroll
        for (int c = 0; c < CPL; ++c)
          acc[h][c] = fmaf(wv[h], f[c], acc[h][c]);
    };
    auto loadq = [&](int src) -> uint2 {
      if (CPL == 4) return *(const uint2*)(tb + (size_t)src * CHIN);
      uint2 r; r.x = *(const u32*)(tb + (size_t)src * CHIN); r.y = 0;
      return r;
    };

    int i = s;
    for (; i + 4 <= e; i += 4) {
      int s0 = __builtin_amdgcn_readfirstlane(colx[2 * i]);
      int s1 = __builtin_amdgcn_readfirstlane(colx[2 * i + 2]);
      int s2 = __builtin_amdgcn_readfirstlane(colx[2 * i + 4]);
      int s3 = __builtin_amdgcn_readfirstlane(colx[2 * i + 6]);
      float4 w0 = wtab[i],     w1 = wtab[i + 1];
      float4 w2 = wtab[i + 2], w3 = wtab[i + 3];
      uint2 q0 = loadq(s0), q1 = loadq(s1), q2 = loadq(s2), q3 = loadq(s3);
      accum(q0, w0); accum(q1, w1); accum(q2, w2); accum(q3, w3);
    }
    for (; i < e; ++i) {
      int s0 = __builtin_amdgcn_readfirstlane(colx[2 * i]);
      float4 w0 = wtab[i];
      accum(loadq(s0), w0);
    }

#pragma unroll
    for (int h = 0; h < 4; ++h) {
      float inv = 1.f / (den[h] + 1e-16f);
      if (CPL == 4) {
        __half2 o0 = __float22half2_rn(make_float2(acc[h][0] * inv, acc[h][1] * inv));
        __half2 o1 = __float22half2_rn(make_float2(acc[h][2] * inv, acc[h][3] * inv));
        *(uint2*)&sA[row * RST + h * CHIN + cb] = make_uint2(*(u32*)&o0, *(u32*)&o1);
      } else {
        __half2 o0 = __float22half2_rn(make_float2(acc[h][0] * inv, acc[h][1] * inv));
        *(u32*)&sA[row * RST + h * CHIN + cb] = *(u32*)&o0;
      }
    }
  }
  __syncthreads();

  // ---- phase 2: out[16x128] = 0.25 * A @ Bm^T + bias ----
  const int t = lane & 15, quad = lane >> 4;
  f32x4 acc0 = (f32x4){0.f, 0.f, 0.f, 0.f};
  f32x4 acc1 = (f32x4){0.f, 0.f, 0.f, 0.f};
  const char* gB0 = (const char*)Bm + ((size_t)(wave * 32 + t) * K + quad * 8) * 2;
  const char* gB1 = gB0 + (size_t)16 * K * 2;
#pragma unroll 4
  for (int k0 = 0; k0 < K; k0 += 32) {
    f16x8 b0 = *(const f16x8*)(gB0 + (size_t)k0 * 2);
    f16x8 b1 = *(const f16x8*)(gB1 + (size_t)k0 * 2);
    f16x8 a = *(const f16x8*)&sA[t * RST + k0 + quad * 8];
    acc0 = __builtin_amdgcn_mfma_f32_16x16x32_f16(a, b0, acc0, 0, 0, 0);
    acc1 = __builtin_amdgcn_mfma_f32_16x16x32_f16(a, b1, acc1, 0, 0, 0);
  }

  const int n0 = wave * 32 + t;
  const float bv0 = bias[n0], bv1 = bias[n0 + 16];
#pragma unroll
  for (int r = 0; r < 4; ++r) {
    int m = quad * 4 + r;                 // C/D: row = quad*4+reg
    int node = base + m;
    float v0 = 0.25f * acc0[r] + bv0;
    float v1 = 0.25f * acc1[r] + bv1;
    if (HALF_OUT) {
      ((__half*)outv)[(size_t)node * 128 + n0]      = __float2half(v0);
      ((__half*)outv)[(size_t)node * 128 + n0 + 16] = __float2half(v1);
    } else {
      ((float*)outv)[(size_t)node * 128 + n0]      = v0;
      ((float*)outv)[(size_t)node * 128 + n0 + 16] = v1;
    }
  }
}

// ---------------- launch ----------------

extern "C" void kernel_launch(void* const* d_in, const int* in_sizes, int n_in,
                              void* d_out, int out_size, void* d_ws, size_t ws_size,
                              hipStream_t stream) {
  const float* x      = (const float*)d_in[0];
  const int*   ei     = (const int*)  d_in[1];
  const float* W1     = (const float*)d_in[2];
  const float* att_s1 = (const float*)d_in[3];
  const float* att_d1 = (const float*)d_in[4];
  const float* b1     = (const float*)d_in[5];
  const float* W2     = (const float*)d_in[6];
  const float* att_s2 = (const float*)d_in[7];
  const float* att_d2 = (const float*)d_in[8];
  const float* b2     = (const float*)d_in[9];
  float* out = (float*)d_out;

  char* ws = (char*)d_ws;
  size_t off = 0;
  auto alloc = [&](size_t bytes) -> void* {
    void* p = ws + off;
    off += (bytes + 255) & ~(size_t)255;
    return p;
  };
  __half* x16  = (__half*)alloc((size_t)N_NODES * 256 * 2);  // 25.6 MB
  __half* out1 = (__half*)alloc((size_t)N_NODES * 128 * 2);  // 12.8 MB (no alias:
                                                             // fused1 reads x16)
  __half* B1p  = (__half*)alloc((size_t)128 * 1024 * 2);
  __half* B2p  = (__half*)alloc((size_t)128 * 512 * 2);
  float* ws1 = (float*)alloc(4 * 256 * 4);
  float* wd1 = (float*)alloc(4 * 256 * 4);
  float* ws2 = (float*)alloc(4 * 128 * 4);
  float* wd2 = (float*)alloc(4 * 128 * 4);
  float* as1 = (float*)alloc((size_t)N_NODES * 4 * 4);
  float* ad1 = (float*)alloc((size_t)N_NODES * 4 * 4);
  float* as2 = (float*)alloc((size_t)N_NODES * 4 * 4);
  float* ad2 = (float*)alloc((size_t)N_NODES * 4 * 4);
  int*   row_ptr = (int*)alloc((size_t)(N_NODES + 1) * 4);
  int*   deg     = (int*)alloc((size_t)N_NODES * 4);
  int*   bsum    = (int*)alloc((size_t)256 * 4);
  int*   epos    = (int*)alloc((size_t)E_TOT * 4);          // 3.4 MB
  int2*  col2    = (int2*)alloc((size_t)E_TOT * 8);         // 6.8 MB
  float4* wtab   = (float4*)alloc((size_t)E_TOT * 16);      // 13.6 MB

  const int edge_blocks = (E_TOT + 255) / 256;
  const int node_wave_blocks = (N_NODES + 3) / 4;   // 12500

  hipMemsetAsync(deg, 0, (size_t)N_NODES * 4, stream);
  prep<<<EB + 208, 256, 0, stream>>>(ei, deg, epos, W1, B1p, W2, B2p,
                                     att_s1, att_d1, att_s2, att_d2,
                                     ws1, wd1, ws2, wd2);
  scan_blocks<<<SBLK, 256, 0, stream>>>(deg, row_ptr, bsum);
  scan_tops<<<1, 256, 0, stream>>>(bsum);
  scan_add<<<SBLK, 256, 0, stream>>>(bsum, row_ptr);
  scatter_pos<<<edge_blocks, 256, 0, stream>>>(ei, epos, row_ptr, col2);

  // layer 1
  prep_x<<<node_wave_blocks, 256, 0, stream>>>(x, ws1, wd1, x16, as1, ad1);
  edge_weights<<<edge_blocks, 256, 0, stream>>>(col2, as1, ad1, wtab);
  gat_fused<4, true><<<FBLK, 256, 0, stream>>>(x16, wtab, row_ptr, col2,
                                               B1p, b1, out1);

  // layer 2
  score2<<<node_wave_blocks, 256, 0, stream>>>(out1, ws2, wd2, as2, ad2);
  edge_weights<<<edge_blocks, 256, 0, stream>>>(col2, as2, ad2, wtab);
  gat_fused<2, false><<<FBLK, 256, 0, stream>>>(out1, wtab, row_ptr, col2,
                                                B2p, b2, out);
}

// Round 10
// 412.108 us; speedup vs baseline: 1.0870x; 1.0870x over previous
//
#include <hip/hip_runtime.h>
#include <hip/hip_fp16.h>
#include <math.h>

#define N_NODES 50000
#define MPAD    50176              /* padded rows = 784*64 */
#define N_EDGES 800000
#define E_TOT   (N_EDGES + N_NODES)
#define EB      ((E_TOT + 255) / 256)   /* 3321 edge blocks in prep */
#define HEADS   4
#define NEG_SLOPE 0.2f
#define SBLK    ((N_NODES + 255) / 256)  /* 196 scan blocks */

typedef unsigned int u32;
typedef unsigned long long u64;
typedef unsigned short u16;
typedef __attribute__((ext_vector_type(8))) _Float16 f16x8;
typedef __attribute__((ext_vector_type(4))) float f32x4;

// =====================================================================
// DUAL-FORM GAT (r16): aggregate PRE-transform features, GEMM after.
// r16 = revert of r15's fusion (FALSIFIED: gather is outstanding-request-
// rate bound; fusing GEMM cut occupancy 66->39% + added intra-block degree
// imbalance + barrier -> gather rate 4.25->1.43 TB/s, kernel 72->158us.
// The agg->HBM->gemm round-trip is the CHEAPER coupling.)
//   - agg: r13's 4-edge unroll (8-unroll was 72->74.5us, also reverted)
//   - gemm: r14's 64x128 tile (grid 784 = ~3 blocks/CU)
//   - NEW: non-temporal stores on agg output. agg1 streams 100MB through
//     L2 while its gather wants the 25.6MB x16 table resident; NT
//     (write-around) stops the eviction. Bit-identical values.
// =====================================================================

// ---------------- prep: degree count (+epos) + W permute-casts + w~ ---------

__global__ __launch_bounds__(256) void prep(const int* __restrict__ ei,
                                            int* __restrict__ deg,
                                            int* __restrict__ epos,
                                            const float* __restrict__ W1,
                                            __half* __restrict__ B1,
                                            const float* __restrict__ W2,
                                            __half* __restrict__ B2,
                                            const float* __restrict__ att_s1,
                                            const float* __restrict__ att_d1,
                                            const float* __restrict__ att_s2,
                                            const float* __restrict__ att_d2,
                                            float* __restrict__ ws1,
                                            float* __restrict__ wd1,
                                            float* __restrict__ ws2,
                                            float* __restrict__ wd2) {
  int b = blockIdx.x, tid = threadIdx.x;
  if (b < EB) {
    int e = b * 256 + tid;
    if (e < E_TOT) {
      int dst = (e < N_EDGES) ? ei[N_EDGES + e] : (e - N_EDGES);
      epos[e] = atomicAdd(&deg[dst], 1);
    }
    return;
  }
  if (b < EB + 128) {
    // W1[512x256] -> B1'[j=0..127][k=h*256+c]: B1'[j][h*256+c] = W1[h*128+j][c]
    int k4 = (b - EB) * 256 + tid;                 // 32768 float4
    float4 v = ((const float4*)W1)[k4];
    __half2 h01 = __float22half2_rn(make_float2(v.x, v.y));
    __half2 h23 = __float22half2_rn(make_float2(v.z, v.w));
    uint2 pk = make_uint2(*(u32*)&h01, *(u32*)&h23);
    int r = k4 >> 6, h = r >> 7, j = r & 127;      // r = W1 row, 4 elems/chunk
    ((uint2*)B1)[j * 256 + h * 64 + (k4 & 63)] = pk;
    return;
  }
  if (b < EB + 192) {
    // W2[512x128] -> B2'[j][h*128+c] = W2[h*128+j][c]
    int k4 = (b - EB - 128) * 256 + tid;           // 16384 float4
    float4 v = ((const float4*)W2)[k4];
    __half2 h01 = __float22half2_rn(make_float2(v.x, v.y));
    __half2 h23 = __float22half2_rn(make_float2(v.z, v.w));
    uint2 pk = make_uint2(*(u32*)&h01, *(u32*)&h23);
    int r = k4 >> 5, h = r >> 7, j = r & 127;
    ((uint2*)B2)[j * 128 + h * 32 + (k4 & 31)] = pk;
    return;
  }
  // w~ vectors: w~[h][k] = sum_c att[h][c] * W[h*128+c][k]
  int bw = b - (EB + 192);                         // 0..15
  int h = bw & 3;
  if (bw < 8) {
    const float* att = (bw < 4) ? att_s1 : att_d1;
    float* o = (bw < 4) ? ws1 : wd1;
    int k = tid;                                   // 0..255
    float acc = 0.f;
    for (int c = 0; c < 128; ++c)
      acc = fmaf(att[h * 128 + c], W1[(size_t)(h * 128 + c) * 256 + k], acc);
    o[h * 256 + k] = acc;
  } else {
    const float* att = (bw < 12) ? att_s2 : att_d2;
    float* o = (bw < 12) ? ws2 : wd2;
    if (tid < 128) {
      int k = tid;
      float acc = 0.f;
      for (int c = 0; c < 128; ++c)
        acc = fmaf(att[h * 128 + c], W2[(size_t)(h * 128 + c) * 128 + k], acc);
      o[h * 128 + k] = acc;
    }
  }
}

// ---------------- device-wide degree scan (3 tiny launches) ----------------

__global__ __launch_bounds__(256) void scan_blocks(const int* __restrict__ deg,
                                                   int* __restrict__ row_ptr,
                                                   int* __restrict__ bsum) {
  __shared__ int sh[256];
  int tid = threadIdx.x;
  int idx = blockIdx.x * 256 + tid;
  int v = (idx < N_NODES) ? deg[idx] : 0;
  sh[tid] = v;
  __syncthreads();
#pragma unroll
  for (int off = 1; off < 256; off <<= 1) {
    int t = (tid >= off) ? sh[tid - off] : 0;
    __syncthreads();
    sh[tid] += t;
    __syncthreads();
  }
  if (idx < N_NODES) row_ptr[idx + 1] = sh[tid];
  if (tid == 255) bsum[blockIdx.x] = sh[255];
}

__global__ __launch_bounds__(256) void scan_tops(int* __restrict__ bsum) {
  __shared__ int sh[256];
  int tid = threadIdx.x;
  int v = (tid < SBLK) ? bsum[tid] : 0;
  sh[tid] = v;
  __syncthreads();
#pragma unroll
  for (int off = 1; off < 256; off <<= 1) {
    int t = (tid >= off) ? sh[tid - off] : 0;
    __syncthreads();
    sh[tid] += t;
    __syncthreads();
  }
  if (tid < SBLK) bsum[tid] = sh[tid] - v;   // exclusive
}

__global__ __launch_bounds__(256) void scan_add(const int* __restrict__ bsum,
                                                int* __restrict__ row_ptr) {
  int idx = blockIdx.x * 256 + threadIdx.x;
  int off = bsum[blockIdx.x];
  if (idx < N_NODES) row_ptr[idx + 1] += off;
  if (idx == 0) row_ptr[0] = 0;
}

__device__ __forceinline__ float leaky_exp(float a) {
  a = (a >= 0.f) ? a : NEG_SLOPE * a;
  return __expf(a);
}

// ---------------- scatter: no atomics, one packed 8B write per edge --------

__global__ __launch_bounds__(256) void scatter_pos(const int* __restrict__ ei,
                                                   const int* __restrict__ epos,
                                                   const int* __restrict__ row_ptr,
                                                   int2* __restrict__ col2) {
  int e = blockIdx.x * 256 + threadIdx.x;
  if (e >= E_TOT) return;
  int src, dst;
  if (e < N_EDGES) { src = ei[e]; dst = ei[N_EDGES + e]; }
  else             { src = e - N_EDGES; dst = src; }
  int slot = row_ptr[dst] + epos[e];
  col2[slot] = make_int2(src, dst);
}

// ---------------- edge weights in CSR-slot order (both layers) -------------

__global__ __launch_bounds__(256) void edge_weights(const int2* __restrict__ col2,
                                                    const float* __restrict__ as_,
                                                    const float* __restrict__ ad_,
                                                    float4* __restrict__ wtab) {
  int i = blockIdx.x * 256 + threadIdx.x;
  if (i >= E_TOT) return;
  int2 sd = col2[i];
  float4 a = ((const float4*)as_)[sd.x];
  float4 d = ((const float4*)ad_)[sd.y];
  float4 w;
  w.x = leaky_exp(a.x + d.x);
  w.y = leaky_exp(a.y + d.y);
  w.z = leaky_exp(a.z + d.z);
  w.w = leaky_exp(a.w + d.w);
  wtab[i] = w;
}

// ---------------- prep_x: x fp32->fp16 cast + layer-1 scores ----------------

__global__ __launch_bounds__(256) void prep_x(const float* __restrict__ x,
                                              const float* __restrict__ ws1,
                                              const float* __restrict__ wd1,
                                              __half* __restrict__ x16,
                                              float* __restrict__ as_,
                                              float* __restrict__ ad_) {
  int node = (blockIdx.x * 256 + threadIdx.x) >> 6;
  if (node >= N_NODES) return;
  int lane = threadIdx.x & 63;
  int c4 = lane * 4;
  f32x4 xv = *(const f32x4*)(x + (size_t)node * 256 + c4);
  __half2 h01 = __float22half2_rn(make_float2(xv[0], xv[1]));
  __half2 h23 = __float22half2_rn(make_float2(xv[2], xv[3]));
  uint2 pk = make_uint2(*(u32*)&h01, *(u32*)&h23);
  *(uint2*)(x16 + (size_t)node * 256 + c4) = pk;
  float p[8];
#pragma unroll
  for (int v = 0; v < 4; ++v) {
    f32x4 w = *(const f32x4*)(ws1 + v * 256 + c4);
    p[v] = xv[0] * w[0] + xv[1] * w[1] + xv[2] * w[2] + xv[3] * w[3];
    f32x4 u = *(const f32x4*)(wd1 + v * 256 + c4);
    p[4 + v] = xv[0] * u[0] + xv[1] * u[1] + xv[2] * u[2] + xv[3] * u[3];
  }
#pragma unroll
  for (int k = 0; k < 8; ++k)
#pragma unroll
    for (int m = 1; m < 64; m <<= 1)
      p[k] += __shfl_xor(p[k], m, 64);
  if (lane == 0) {
    *(float4*)(as_ + (size_t)node * 4) = make_float4(p[0], p[1], p[2], p[3]);
    *(float4*)(ad_ + (size_t)node * 4) = make_float4(p[4], p[5], p[6], p[7]);
  }
}

// ---------------- score2: layer-2 scores from h (128 ch fp16) ---------------

__global__ __launch_bounds__(256) void score2(const __half* __restrict__ hrow,
                                              const float* __restrict__ ws2,
                                              const float* __restrict__ wd2,
                                              float* __restrict__ as_,
                                              float* __restrict__ ad_) {
  int node = (blockIdx.x * 256 + threadIdx.x) >> 6;
  if (node >= N_NODES) return;
  int lane = threadIdx.x & 63, c = lane * 2;
  float2 f = __half22float2(*(const __half2*)(hrow + (size_t)node * 128 + c));
  float p[8];
#pragma unroll
  for (int v = 0; v < 4; ++v) {
    float2 w = *(const float2*)(ws2 + v * 128 + c);
    p[v] = f.x * w.x + f.y * w.y;
    float2 u = *(const float2*)(wd2 + v * 128 + c);
    p[4 + v] = f.x * u.x + f.y * u.y;
  }
#pragma unroll
  for (int k = 0; k < 8; ++k)
#pragma unroll
    for (int m = 1; m < 64; m <<= 1)
      p[k] += __shfl_xor(p[k], m, 64);
  if (lane == 0) {
    *(float4*)(as_ + (size_t)node * 4) = make_float4(p[0], p[1], p[2], p[3]);
    *(float4*)(ad_ + (size_t)node * 4) = make_float4(p[4], p[5], p[6], p[7]);
  }
}

// ---------------- pre-transform aggregation with PRECOMPUTED weights -------
// one wave per dst node; lane holds CPL channels; weights w[e,h] read as a
// sequential 16B broadcast (CSR-slot order). 4-edge unroll (8 regressed:
// service-bound). NT stores on output: keep the gather table L2-resident.

template <int CPL>   // 4 -> CHIN=256 (layer 1), 2 -> CHIN=128 (layer 2)
__global__ __launch_bounds__(256) void gat_aggregate_w(
    const __half* __restrict__ tbl, const float4* __restrict__ wtab,
    const int* __restrict__ row_ptr, const int2* __restrict__ col2,
    __half* __restrict__ agg) {
  constexpr int CHIN = CPL * 64;
  const int* colx = (const int*)col2;               // .x at index 2*i
  int node = (blockIdx.x * 256 + threadIdx.x) >> 6;   // wave-uniform
  if (node >= N_NODES) return;
  int lane = threadIdx.x & 63, cb = lane * CPL;
  const __half* tb = tbl + cb;
  int s = __builtin_amdgcn_readfirstlane(row_ptr[node]);
  int e = __builtin_amdgcn_readfirstlane(row_ptr[node + 1]);

  float acc[4][CPL];
#pragma unroll
  for (int h = 0; h < 4; ++h)
#pragma unroll
    for (int c = 0; c < CPL; ++c) acc[h][c] = 0.f;
  float den[4] = {0.f, 0.f, 0.f, 0.f};

  auto accum = [&](uint2 q, float4 w) {
    float wv[4] = {w.x, w.y, w.z, w.w};
#pragma unroll
    for (int h = 0; h < 4; ++h) den[h] += wv[h];
    float f[CPL];
    float2 f0 = __half22float2(*(__half2*)&q.x);
    f[0] = f0.x; f[1] = f0.y;
    if (CPL == 4) {
      float2 f1 = __half22float2(*(__half2*)&q.y);
      f[2] = f1.x; f[3] = f1.y;
    }
#pragma unroll
    for (int h = 0; h < 4; ++h)
#pragma unroll
      for (int c = 0; c < CPL; ++c)
        acc[h][c] = fmaf(wv[h], f[c], acc[h][c]);
  };
  auto loadq = [&](int src) -> uint2 {
    if (CPL == 4) return *(const uint2*)(tb + (size_t)src * CHIN);
    uint2 r; r.x = *(const u32*)(tb + (size_t)src * CHIN); r.y = 0;
    return r;
  };

  int i = s;
  for (; i + 4 <= e; i += 4) {
    int s0 = __builtin_amdgcn_readfirstlane(colx[2 * i]);
    int s1 = __builtin_amdgcn_readfirstlane(colx[2 * i + 2]);
    int s2 = __builtin_amdgcn_readfirstlane(colx[2 * i + 4]);
    int s3 = __builtin_amdgcn_readfirstlane(colx[2 * i + 6]);
    float4 w0 = wtab[i],     w1 = wtab[i + 1];
    float4 w2 = wtab[i + 2], w3 = wtab[i + 3];
    uint2 q0 = loadq(s0), q1 = loadq(s1), q2 = loadq(s2), q3 = loadq(s3);
    accum(q0, w0); accum(q1, w1); accum(q2, w2); accum(q3, w3);
  }
  for (; i < e; ++i) {
    int s0 = __builtin_amdgcn_readfirstlane(colx[2 * i]);
    float4 w0 = wtab[i];
    accum(loadq(s0), w0);
  }

#pragma unroll
  for (int h = 0; h < 4; ++h) {
    float inv = 1.f / (den[h] + 1e-16f);
    if (CPL == 4) {
      __half2 o0 = __float22half2_rn(make_float2(acc[h][0] * inv, acc[h][1] * inv));
      __half2 o1 = __float22half2_rn(make_float2(acc[h][2] * inv, acc[h][3] * inv));
      uint2 pk = make_uint2(*(u32*)&o0, *(u32*)&o1);
      __builtin_nontemporal_store(*(u64*)&pk,
          (u64*)(agg + (size_t)node * 4 * CHIN + h * CHIN + cb));
    } else {
      __half2 o0 = __float22half2_rn(make_float2(acc[h][0] * inv, acc[h][1] * inv));
      __builtin_nontemporal_store(*(u32*)&o0,
          (u32*)(agg + (size_t)node * 4 * CHIN + h * CHIN + cb));
    }
  }
}

// ---------------- post-aggregation GEMM: out = 0.25 * A @ B'^T + bias ------
// A[MPAD x K] fp16 (agg, head-concat K), B'[128 x K] fp16, out [MPAD x 128].
// 64x128 tile, 256 thr = 4 waves (2 row x 2 col), acc[2][4], 12 KB LDS.
// Grid 784 = ~3 blocks/CU.

#define GLD16(gp, lp)                                                          \
  __builtin_amdgcn_global_load_lds(                                            \
      (const __attribute__((address_space(1))) u32*)(gp),                      \
      (__attribute__((address_space(3))) u32*)(lp), 16, 0, 0)

template <int K, bool HALF_OUT>
__global__ __launch_bounds__(256, 4) void gemm_mean(
    const __half* __restrict__ A, const __half* __restrict__ Bm,
    const float* __restrict__ bias, void* __restrict__ outv) {
  __shared__ u16 sA[64 * 32];    // 4 KB
  __shared__ u16 sB[128 * 32];   // 8 KB
  const int tid = threadIdx.x, lane = tid & 63, wave = tid >> 6;  // 0..3
  const int m0 = blockIdx.x * 64;
  const int wm = (wave >> 1) * 32, wn = (wave & 1) * 64;
  const int t = lane & 15, quad = lane >> 4;

  f32x4 acc[2][4];
#pragma unroll
  for (int i = 0; i < 2; i++)
#pragma unroll
    for (int j = 0; j < 4; j++) acc[i][j] = (f32x4){0.f, 0.f, 0.f, 0.f};

  const char* gpA; u32 offA;
  {
    int row = tid >> 2, w16 = tid & 3;  // 256 chunks: 64 rows x 4
    gpA = (const char*)A + ((size_t)(m0 + row) * K) * 2 + w16 * 16;
    offA = (u32)tid * 16;
  }
  const char* gpB[2]; u32 offB[2];
#pragma unroll
  for (int r = 0; r < 2; ++r) {
    int c = tid + r * 256;              // 512 chunks: 128 rows x 4
    int row = c >> 2, w16 = c & 3;
    gpB[r] = (const char*)Bm + ((size_t)row * K) * 2 + w16 * 16;
    offB[r] = (u32)c * 16;
  }

  for (int k0 = 0; k0 < K; k0 += 32) {
    __syncthreads();
    GLD16(gpA, (char*)sA + offA); gpA += 64;
#pragma unroll
    for (int r = 0; r < 2; ++r) { GLD16(gpB[r], (char*)sB + offB[r]); gpB[r] += 64; }
    __syncthreads();

    f16x8 a[2], b[4];
#pragma unroll
    for (int i = 0; i < 2; ++i)
      a[i] = *(const f16x8*)&sA[(wm + t + i * 16) * 32 + quad * 8];
#pragma unroll
    for (int j = 0; j < 4; ++j)
      b[j] = *(const f16x8*)&sB[(wn + t + j * 16) * 32 + quad * 8];
#pragma unroll
    for (int i = 0; i < 2; ++i)
#pragma unroll
      for (int j = 0; j < 4; ++j)
        acc[i][j] = __builtin_amdgcn_mfma_f32_16x16x32_f16(a[i], b[j], acc[i][j], 0, 0, 0);
  }

  float bv[4];
#pragma unroll
  for (int j = 0; j < 4; ++j) bv[j] = bias[wn + j * 16 + t];
#pragma unroll
  for (int i = 0; i < 2; ++i)
#pragma unroll
    for (int j = 0; j < 4; ++j)
#pragma unroll
      for (int r = 0; r < 4; ++r) {
        int m = m0 + wm + i * 16 + quad * 4 + r;   // C/D: col=lane&15, row=quad*4+reg
        if (m < N_NODES) {
          int n = wn + j * 16 + t;
          float v = 0.25f * acc[i][j][r] + bv[j];
          if (HALF_OUT) ((__half*)outv)[(size_t)m * 128 + n] = __float2half(v);
          else          ((float*)outv)[(size_t)m * 128 + n] = v;
        }
      }
}

// ---------------- launch ----------------

extern "C" void kernel_launch(void* const* d_in, const int* in_sizes, int n_in,
                              void* d_out, int out_size, void* d_ws, size_t ws_size,
                              hipStream_t stream) {
  const float* x      = (const float*)d_in[0];
  const int*   ei     = (const int*)  d_in[1];
  const float* W1     = (const float*)d_in[2];
  const float* att_s1 = (const float*)d_in[3];
  const float* att_d1 = (const float*)d_in[4];
  const float* b1     = (const float*)d_in[5];
  const float* W2     = (const float*)d_in[6];
  const float* att_s2 = (const float*)d_in[7];
  const float* att_d2 = (const float*)d_in[8];
  const float* b2     = (const float*)d_in[9];
  float* out = (float*)d_out;

  char* ws = (char*)d_ws;
  size_t off = 0;
  auto alloc = [&](size_t bytes) -> void* {
    void* p = ws + off;
    off += (bytes + 255) & ~(size_t)255;
    return p;
  };
  __half* x16  = (__half*)alloc((size_t)MPAD * 256 * 2);    // 25.7 MB
  __half* agg1 = (__half*)alloc((size_t)MPAD * 1024 * 2);   // 102.8 MB
  __half* B1p  = (__half*)alloc((size_t)128 * 1024 * 2);
  __half* B2p  = (__half*)alloc((size_t)128 * 512 * 2);
  float* ws1 = (float*)alloc(4 * 256 * 4);
  float* wd1 = (float*)alloc(4 * 256 * 4);
  float* ws2 = (float*)alloc(4 * 128 * 4);
  float* wd2 = (float*)alloc(4 * 128 * 4);
  float* as1 = (float*)alloc((size_t)N_NODES * 4 * 4);
  float* ad1 = (float*)alloc((size_t)N_NODES * 4 * 4);
  float* as2 = (float*)alloc((size_t)N_NODES * 4 * 4);
  float* ad2 = (float*)alloc((size_t)N_NODES * 4 * 4);
  int*   row_ptr = (int*)alloc((size_t)(N_NODES + 1) * 4);
  int*   deg     = (int*)alloc((size_t)N_NODES * 4);
  int*   bsum    = (int*)alloc((size_t)256 * 4);
  int*   epos    = (int*)alloc((size_t)E_TOT * 4);          // 3.4 MB
  int2*  col2    = (int2*)alloc((size_t)E_TOT * 8);         // 6.8 MB
  float4* wtab   = (float4*)alloc((size_t)E_TOT * 16);      // 13.6 MB

  // lifetime aliases (stream-ordered, no concurrent use):
  //   out1 (12.8 MB)  reuses x16   (x16 dead after aggregate-1)
  //   agg2 (51.4 MB)  reuses agg1  (agg1 dead after gemm_mean-1)
  __half* out1 = x16;
  __half* agg2 = agg1;

  const int edge_blocks = (E_TOT + 255) / 256;
  const int node_wave_blocks = (N_NODES + 3) / 4;   // 12500

  hipMemsetAsync(deg, 0, (size_t)N_NODES * 4, stream);
  prep<<<EB + 208, 256, 0, stream>>>(ei, deg, epos, W1, B1p, W2, B2p,
                                     att_s1, att_d1, att_s2, att_d2,
                                     ws1, wd1, ws2, wd2);
  scan_blocks<<<SBLK, 256, 0, stream>>>(deg, row_ptr, bsum);
  scan_tops<<<1, 256, 0, stream>>>(bsum);
  scan_add<<<SBLK, 256, 0, stream>>>(bsum, row_ptr);
  scatter_pos<<<edge_blocks, 256, 0, stream>>>(ei, epos, row_ptr, col2);

  // layer 1
  prep_x<<<node_wave_blocks, 256, 0, stream>>>(x, ws1, wd1, x16, as1, ad1);
  edge_weights<<<edge_blocks, 256, 0, stream>>>(col2, as1, ad1, wtab);
  gat_aggregate_w<4><<<node_wave_blocks, 256, 0, stream>>>(
      x16, wtab, row_ptr, col2, agg1);
  gemm_mean<1024, true><<<MPAD / 64, 256, 0, stream>>>(agg1, B1p, b1, out1);

  // layer 2
  score2<<<node_wave_blocks, 256, 0, stream>>>(out1, ws2, wd2, as2, ad2);
  edge_weights<<<edge_blocks, 256, 0, stream>>>(col2, as2, ad2, wtab);
  gat_aggregate_w<2><<<node_wave_blocks, 256, 0, stream>>>(
      out1, wtab, row_ptr, col2, agg2);
  gemm_mean<512, false><<<MPAD / 64, 256, 0, stream>>>(agg2, B2p, b2, out);
}

// Round 11
// 391.598 us; speedup vs baseline: 1.1440x; 1.0524x over previous
//
#include <hip/hip_runtime.h>
#include <hip/hip_fp16.h>
#include <math.h>

#define N_NODES 50000
#define MPAD    50176              /* padded rows = 784*64 */
#define N_EDGES 800000
#define E_TOT   (N_EDGES + N_NODES)
#define EB      ((E_TOT + 255) / 256)   /* 3321 edge blocks in prep */
#define HEADS   4
#define NEG_SLOPE 0.2f
#define SBLK    ((N_NODES + 255) / 256)  /* 196 scan blocks */

typedef unsigned int u32;
typedef unsigned short u16;
typedef __attribute__((ext_vector_type(8))) _Float16 f16x8;
typedef __attribute__((ext_vector_type(4))) float f32x4;

// =====================================================================
// DUAL-FORM GAT (r17): aggregate PRE-transform features, GEMM after.
// r17 = r16 minus the NT stores (FALSIFIED: agg FETCH only dropped 5MB
// -- the 205MB FETCH is 8 XCDs x 25.6MB table, already the algorithmic
// floor -- while gemm_mean lost its L2 hits on the freshly-written agg:
// non-agg time +21us. Plain stores restored; values bit-identical).
// Composite of all verified wins:
//   - dual-form (aggregate pre-transform, GEMM after)    [r10: -41us]
//   - edge weights precomputed edge-parallel, slot-order [r11: -32us]
//   - device-wide 3-launch degree scan                   [r12: -82us]
//   - atomic-free scatter via saved epos, packed int2    [r13: -33us]
//   - gemm 64x128 tile, grid 784 (~3-4 blocks/CU)        [r14]
//   - agg 4-edge unroll (8 regressed: service-bound)     [r8/r10]
// =====================================================================

// ---------------- prep: degree count (+epos) + W permute-casts + w~ ---------

__global__ __launch_bounds__(256) void prep(const int* __restrict__ ei,
                                            int* __restrict__ deg,
                                            int* __restrict__ epos,
                                            const float* __restrict__ W1,
                                            __half* __restrict__ B1,
                                            const float* __restrict__ W2,
                                            __half* __restrict__ B2,
                                            const float* __restrict__ att_s1,
                                            const float* __restrict__ att_d1,
                                            const float* __restrict__ att_s2,
                                            const float* __restrict__ att_d2,
                                            float* __restrict__ ws1,
                                            float* __restrict__ wd1,
                                            float* __restrict__ ws2,
                                            float* __restrict__ wd2) {
  int b = blockIdx.x, tid = threadIdx.x;
  if (b < EB) {
    int e = b * 256 + tid;
    if (e < E_TOT) {
      int dst = (e < N_EDGES) ? ei[N_EDGES + e] : (e - N_EDGES);
      epos[e] = atomicAdd(&deg[dst], 1);
    }
    return;
  }
  if (b < EB + 128) {
    // W1[512x256] -> B1'[j=0..127][k=h*256+c]: B1'[j][h*256+c] = W1[h*128+j][c]
    int k4 = (b - EB) * 256 + tid;                 // 32768 float4
    float4 v = ((const float4*)W1)[k4];
    __half2 h01 = __float22half2_rn(make_float2(v.x, v.y));
    __half2 h23 = __float22half2_rn(make_float2(v.z, v.w));
    uint2 pk = make_uint2(*(u32*)&h01, *(u32*)&h23);
    int r = k4 >> 6, h = r >> 7, j = r & 127;      // r = W1 row, 4 elems/chunk
    ((uint2*)B1)[j * 256 + h * 64 + (k4 & 63)] = pk;
    return;
  }
  if (b < EB + 192) {
    // W2[512x128] -> B2'[j][h*128+c] = W2[h*128+j][c]
    int k4 = (b - EB - 128) * 256 + tid;           // 16384 float4
    float4 v = ((const float4*)W2)[k4];
    __half2 h01 = __float22half2_rn(make_float2(v.x, v.y));
    __half2 h23 = __float22half2_rn(make_float2(v.z, v.w));
    uint2 pk = make_uint2(*(u32*)&h01, *(u32*)&h23);
    int r = k4 >> 5, h = r >> 7, j = r & 127;
    ((uint2*)B2)[j * 128 + h * 32 + (k4 & 31)] = pk;
    return;
  }
  // w~ vectors: w~[h][k] = sum_c att[h][c] * W[h*128+c][k]
  int bw = b - (EB + 192);                         // 0..15
  int h = bw & 3;
  if (bw < 8) {
    const float* att = (bw < 4) ? att_s1 : att_d1;
    float* o = (bw < 4) ? ws1 : wd1;
    int k = tid;                                   // 0..255
    float acc = 0.f;
    for (int c = 0; c < 128; ++c)
      acc = fmaf(att[h * 128 + c], W1[(size_t)(h * 128 + c) * 256 + k], acc);
    o[h * 256 + k] = acc;
  } else {
    const float* att = (bw < 12) ? att_s2 : att_d2;
    float* o = (bw < 12) ? ws2 : wd2;
    if (tid < 128) {
      int k = tid;
      float acc = 0.f;
      for (int c = 0; c < 128; ++c)
        acc = fmaf(att[h * 128 + c], W2[(size_t)(h * 128 + c) * 128 + k], acc);
      o[h * 128 + k] = acc;
    }
  }
}

// ---------------- device-wide degree scan (3 tiny launches) ----------------

__global__ __launch_bounds__(256) void scan_blocks(const int* __restrict__ deg,
                                                   int* __restrict__ row_ptr,
                                                   int* __restrict__ bsum) {
  __shared__ int sh[256];
  int tid = threadIdx.x;
  int idx = blockIdx.x * 256 + tid;
  int v = (idx < N_NODES) ? deg[idx] : 0;
  sh[tid] = v;
  __syncthreads();
#pragma unroll
  for (int off = 1; off < 256; off <<= 1) {
    int t = (tid >= off) ? sh[tid - off] : 0;
    __syncthreads();
    sh[tid] += t;
    __syncthreads();
  }
  if (idx < N_NODES) row_ptr[idx + 1] = sh[tid];
  if (tid == 255) bsum[blockIdx.x] = sh[255];
}

__global__ __launch_bounds__(256) void scan_tops(int* __restrict__ bsum) {
  __shared__ int sh[256];
  int tid = threadIdx.x;
  int v = (tid < SBLK) ? bsum[tid] : 0;
  sh[tid] = v;
  __syncthreads();
#pragma unroll
  for (int off = 1; off < 256; off <<= 1) {
    int t = (tid >= off) ? sh[tid - off] : 0;
    __syncthreads();
    sh[tid] += t;
    __syncthreads();
  }
  if (tid < SBLK) bsum[tid] = sh[tid] - v;   // exclusive
}

__global__ __launch_bounds__(256) void scan_add(const int* __restrict__ bsum,
                                                int* __restrict__ row_ptr) {
  int idx = blockIdx.x * 256 + threadIdx.x;
  int off = bsum[blockIdx.x];
  if (idx < N_NODES) row_ptr[idx + 1] += off;
  if (idx == 0) row_ptr[0] = 0;
}

__device__ __forceinline__ float leaky_exp(float a) {
  a = (a >= 0.f) ? a : NEG_SLOPE * a;
  return __expf(a);
}

// ---------------- scatter: no atomics, one packed 8B write per edge --------

__global__ __launch_bounds__(256) void scatter_pos(const int* __restrict__ ei,
                                                   const int* __restrict__ epos,
                                                   const int* __restrict__ row_ptr,
                                                   int2* __restrict__ col2) {
  int e = blockIdx.x * 256 + threadIdx.x;
  if (e >= E_TOT) return;
  int src, dst;
  if (e < N_EDGES) { src = ei[e]; dst = ei[N_EDGES + e]; }
  else             { src = e - N_EDGES; dst = src; }
  int slot = row_ptr[dst] + epos[e];
  col2[slot] = make_int2(src, dst);
}

// ---------------- edge weights in CSR-slot order (both layers) -------------

__global__ __launch_bounds__(256) void edge_weights(const int2* __restrict__ col2,
                                                    const float* __restrict__ as_,
                                                    const float* __restrict__ ad_,
                                                    float4* __restrict__ wtab) {
  int i = blockIdx.x * 256 + threadIdx.x;
  if (i >= E_TOT) return;
  int2 sd = col2[i];
  float4 a = ((const float4*)as_)[sd.x];
  float4 d = ((const float4*)ad_)[sd.y];
  float4 w;
  w.x = leaky_exp(a.x + d.x);
  w.y = leaky_exp(a.y + d.y);
  w.z = leaky_exp(a.z + d.z);
  w.w = leaky_exp(a.w + d.w);
  wtab[i] = w;
}

// ---------------- prep_x: x fp32->fp16 cast + layer-1 scores ----------------

__global__ __launch_bounds__(256) void prep_x(const float* __restrict__ x,
                                              const float* __restrict__ ws1,
                                              const float* __restrict__ wd1,
                                              __half* __restrict__ x16,
                                              float* __restrict__ as_,
                                              float* __restrict__ ad_) {
  int node = (blockIdx.x * 256 + threadIdx.x) >> 6;
  if (node >= N_NODES) return;
  int lane = threadIdx.x & 63;
  int c4 = lane * 4;
  f32x4 xv = *(const f32x4*)(x + (size_t)node * 256 + c4);
  __half2 h01 = __float22half2_rn(make_float2(xv[0], xv[1]));
  __half2 h23 = __float22half2_rn(make_float2(xv[2], xv[3]));
  uint2 pk = make_uint2(*(u32*)&h01, *(u32*)&h23);
  *(uint2*)(x16 + (size_t)node * 256 + c4) = pk;
  float p[8];
#pragma unroll
  for (int v = 0; v < 4; ++v) {
    f32x4 w = *(const f32x4*)(ws1 + v * 256 + c4);
    p[v] = xv[0] * w[0] + xv[1] * w[1] + xv[2] * w[2] + xv[3] * w[3];
    f32x4 u = *(const f32x4*)(wd1 + v * 256 + c4);
    p[4 + v] = xv[0] * u[0] + xv[1] * u[1] + xv[2] * u[2] + xv[3] * u[3];
  }
#pragma unroll
  for (int k = 0; k < 8; ++k)
#pragma unroll
    for (int m = 1; m < 64; m <<= 1)
      p[k] += __shfl_xor(p[k], m, 64);
  if (lane == 0) {
    *(float4*)(as_ + (size_t)node * 4) = make_float4(p[0], p[1], p[2], p[3]);
    *(float4*)(ad_ + (size_t)node * 4) = make_float4(p[4], p[5], p[6], p[7]);
  }
}

// ---------------- score2: layer-2 scores from h (128 ch fp16) ---------------

__global__ __launch_bounds__(256) void score2(const __half* __restrict__ hrow,
                                              const float* __restrict__ ws2,
                                              const float* __restrict__ wd2,
                                              float* __restrict__ as_,
                                              float* __restrict__ ad_) {
  int node = (blockIdx.x * 256 + threadIdx.x) >> 6;
  if (node >= N_NODES) return;
  int lane = threadIdx.x & 63, c = lane * 2;
  float2 f = __half22float2(*(const __half2*)(hrow + (size_t)node * 128 + c));
  float p[8];
#pragma unroll
  for (int v = 0; v < 4; ++v) {
    float2 w = *(const float2*)(ws2 + v * 128 + c);
    p[v] = f.x * w.x + f.y * w.y;
    float2 u = *(const float2*)(wd2 + v * 128 + c);
    p[4 + v] = f.x * u.x + f.y * u.y;
  }
#pragma unroll
  for (int k = 0; k < 8; ++k)
#pragma unroll
    for (int m = 1; m < 64; m <<= 1)
      p[k] += __shfl_xor(p[k], m, 64);
  if (lane == 0) {
    *(float4*)(as_ + (size_t)node * 4) = make_float4(p[0], p[1], p[2], p[3]);
    *(float4*)(ad_ + (size_t)node * 4) = make_float4(p[4], p[5], p[6], p[7]);
  }
}

// ---------------- pre-transform aggregation with PRECOMPUTED weights -------
// one wave per dst node; lane holds CPL channels; weights w[e,h] read as a
// sequential 16B broadcast (CSR-slot order). 4-edge unroll (8 regressed:
// service-bound). Plain stores (NT regressed: gemm loses L2 hits on agg).

template <int CPL>   // 4 -> CHIN=256 (layer 1), 2 -> CHIN=128 (layer 2)
__global__ __launch_bounds__(256) void gat_aggregate_w(
    const __half* __restrict__ tbl, const float4* __restrict__ wtab,
    const int* __restrict__ row_ptr, const int2* __restrict__ col2,
    __half* __restrict__ agg) {
  constexpr int CHIN = CPL * 64;
  const int* colx = (const int*)col2;               // .x at index 2*i
  int node = (blockIdx.x * 256 + threadIdx.x) >> 6;   // wave-uniform
  if (node >= N_NODES) return;
  int lane = threadIdx.x & 63, cb = lane * CPL;
  const __half* tb = tbl + cb;
  int s = __builtin_amdgcn_readfirstlane(row_ptr[node]);
  int e = __builtin_amdgcn_readfirstlane(row_ptr[node + 1]);

  float acc[4][CPL];
#pragma unroll
  for (int h = 0; h < 4; ++h)
#pragma unroll
    for (int c = 0; c < CPL; ++c) acc[h][c] = 0.f;
  float den[4] = {0.f, 0.f, 0.f, 0.f};

  auto accum = [&](uint2 q, float4 w) {
    float wv[4] = {w.x, w.y, w.z, w.w};
#pragma unroll
    for (int h = 0; h < 4; ++h) den[h] += wv[h];
    float f[CPL];
    float2 f0 = __half22float2(*(__half2*)&q.x);
    f[0] = f0.x; f[1] = f0.y;
    if (CPL == 4) {
      float2 f1 = __half22float2(*(__half2*)&q.y);
      f[2] = f1.x; f[3] = f1.y;
    }
#pragma unroll
    for (int h = 0; h < 4; ++h)
#pragma unroll
      for (int c = 0; c < CPL; ++c)
        acc[h][c] = fmaf(wv[h], f[c], acc[h][c]);
  };
  auto loadq = [&](int src) -> uint2 {
    if (CPL == 4) return *(const uint2*)(tb + (size_t)src * CHIN);
    uint2 r; r.x = *(const u32*)(tb + (size_t)src * CHIN); r.y = 0;
    return r;
  };

  int i = s;
  for (; i + 4 <= e; i += 4) {
    int s0 = __builtin_amdgcn_readfirstlane(colx[2 * i]);
    int s1 = __builtin_amdgcn_readfirstlane(colx[2 * i + 2]);
    int s2 = __builtin_amdgcn_readfirstlane(colx[2 * i + 4]);
    int s3 = __builtin_amdgcn_readfirstlane(colx[2 * i + 6]);
    float4 w0 = wtab[i],     w1 = wtab[i + 1];
    float4 w2 = wtab[i + 2], w3 = wtab[i + 3];
    uint2 q0 = loadq(s0), q1 = loadq(s1), q2 = loadq(s2), q3 = loadq(s3);
    accum(q0, w0); accum(q1, w1); accum(q2, w2); accum(q3, w3);
  }
  for (; i < e; ++i) {
    int s0 = __builtin_amdgcn_readfirstlane(colx[2 * i]);
    float4 w0 = wtab[i];
    accum(loadq(s0), w0);
  }

#pragma unroll
  for (int h = 0; h < 4; ++h) {
    float inv = 1.f / (den[h] + 1e-16f);
    if (CPL == 4) {
      __half2 o0 = __float22half2_rn(make_float2(acc[h][0] * inv, acc[h][1] * inv));
      __half2 o1 = __float22half2_rn(make_float2(acc[h][2] * inv, acc[h][3] * inv));
      *(uint2*)(agg + (size_t)node * 4 * CHIN + h * CHIN + cb) =
          make_uint2(*(u32*)&o0, *(u32*)&o1);
    } else {
      __half2 o0 = __float22half2_rn(make_float2(acc[h][0] * inv, acc[h][1] * inv));
      *(u32*)(agg + (size_t)node * 4 * CHIN + h * CHIN + cb) = *(u32*)&o0;
    }
  }
}

// ---------------- post-aggregation GEMM: out = 0.25 * A @ B'^T + bias ------
// A[MPAD x K] fp16 (agg, head-concat K), B'[128 x K] fp16, out [MPAD x 128].
// 64x128 tile, 256 thr = 4 waves (2 row x 2 col), acc[2][4], 12 KB LDS.
// Grid 784 = ~3-4 blocks/CU.

#define GLD16(gp, lp)                                                          \
  __builtin_amdgcn_global_load_lds(                                            \
      (const __attribute__((address_space(1))) u32*)(gp),                      \
      (__attribute__((address_space(3))) u32*)(lp), 16, 0, 0)

template <int K, bool HALF_OUT>
__global__ __launch_bounds__(256, 4) void gemm_mean(
    const __half* __restrict__ A, const __half* __restrict__ Bm,
    const float* __restrict__ bias, void* __restrict__ outv) {
  __shared__ u16 sA[64 * 32];    // 4 KB
  __shared__ u16 sB[128 * 32];   // 8 KB
  const int tid = threadIdx.x, lane = tid & 63, wave = tid >> 6;  // 0..3
  const int m0 = blockIdx.x * 64;
  const int wm = (wave >> 1) * 32, wn = (wave & 1) * 64;
  const int t = lane & 15, quad = lane >> 4;

  f32x4 acc[2][4];
#pragma unroll
  for (int i = 0; i < 2; i++)
#pragma unroll
    for (int j = 0; j < 4; j++) acc[i][j] = (f32x4){0.f, 0.f, 0.f, 0.f};

  const char* gpA; u32 offA;
  {
    int row = tid >> 2, w16 = tid & 3;  // 256 chunks: 64 rows x 4
    gpA = (const char*)A + ((size_t)(m0 + row) * K) * 2 + w16 * 16;
    offA = (u32)tid * 16;
  }
  const char* gpB[2]; u32 offB[2];
#pragma unroll
  for (int r = 0; r < 2; ++r) {
    int c = tid + r * 256;              // 512 chunks: 128 rows x 4
    int row = c >> 2, w16 = c & 3;
    gpB[r] = (const char*)Bm + ((size_t)row * K) * 2 + w16 * 16;
    offB[r] = (u32)c * 16;
  }

  for (int k0 = 0; k0 < K; k0 += 32) {
    __syncthreads();
    GLD16(gpA, (char*)sA + offA); gpA += 64;
#pragma unroll
    for (int r = 0; r < 2; ++r) { GLD16(gpB[r], (char*)sB + offB[r]); gpB[r] += 64; }
    __syncthreads();

    f16x8 a[2], b[4];
#pragma unroll
    for (int i = 0; i < 2; ++i)
      a[i] = *(const f16x8*)&sA[(wm + t + i * 16) * 32 + quad * 8];
#pragma unroll
    for (int j = 0; j < 4; ++j)
      b[j] = *(const f16x8*)&sB[(wn + t + j * 16) * 32 + quad * 8];
#pragma unroll
    for (int i = 0; i < 2; ++i)
#pragma unroll
      for (int j = 0; j < 4; ++j)
        acc[i][j] = __builtin_amdgcn_mfma_f32_16x16x32_f16(a[i], b[j], acc[i][j], 0, 0, 0);
  }

  float bv[4];
#pragma unroll
  for (int j = 0; j < 4; ++j) bv[j] = bias[wn + j * 16 + t];
#pragma unroll
  for (int i = 0; i < 2; ++i)
#pragma unroll
    for (int j = 0; j < 4; ++j)
#pragma unroll
      for (int r = 0; r < 4; ++r) {
        int m = m0 + wm + i * 16 + quad * 4 + r;   // C/D: col=lane&15, row=quad*4+reg
        if (m < N_NODES) {
          int n = wn + j * 16 + t;
          float v = 0.25f * acc[i][j][r] + bv[j];
          if (HALF_OUT) ((__half*)outv)[(size_t)m * 128 + n] = __float2half(v);
          else          ((float*)outv)[(size_t)m * 128 + n] = v;
        }
      }
}

// ---------------- launch ----------------

extern "C" void kernel_launch(void* const* d_in, const int* in_sizes, int n_in,
                              void* d_out, int out_size, void* d_ws, size_t ws_size,
                              hipStream_t stream) {
  const float* x      = (const float*)d_in[0];
  const int*   ei     = (const int*)  d_in[1];
  const float* W1     = (const float*)d_in[2];
  const float* att_s1 = (const float*)d_in[3];
  const float* att_d1 = (const float*)d_in[4];
  const float* b1     = (const float*)d_in[5];
  const float* W2     = (const float*)d_in[6];
  const float* att_s2 = (const float*)d_in[7];
  const float* att_d2 = (const float*)d_in[8];
  const float* b2     = (const float*)d_in[9];
  float* out = (float*)d_out;

  char* ws = (char*)d_ws;
  size_t off = 0;
  auto alloc = [&](size_t bytes) -> void* {
    void* p = ws + off;
    off += (bytes + 255) & ~(size_t)255;
    return p;
  };
  __half* x16  = (__half*)alloc((size_t)MPAD * 256 * 2);    // 25.7 MB
  __half* agg1 = (__half*)alloc((size_t)MPAD * 1024 * 2);   // 102.8 MB
  __half* B1p  = (__half*)alloc((size_t)128 * 1024 * 2);
  __half* B2p  = (__half*)alloc((size_t)128 * 512 * 2);
  float* ws1 = (float*)alloc(4 * 256 * 4);
  float* wd1 = (float*)alloc(4 * 256 * 4);
  float* ws2 = (float*)alloc(4 * 128 * 4);
  float* wd2 = (float*)alloc(4 * 128 * 4);
  float* as1 = (float*)alloc((size_t)N_NODES * 4 * 4);
  float* ad1 = (float*)alloc((size_t)N_NODES * 4 * 4);
  float* as2 = (float*)alloc((size_t)N_NODES * 4 * 4);
  float* ad2 = (float*)alloc((size_t)N_NODES * 4 * 4);
  int*   row_ptr = (int*)alloc((size_t)(N_NODES + 1) * 4);
  int*   deg     = (int*)alloc((size_t)N_NODES * 4);
  int*   bsum    = (int*)alloc((size_t)256 * 4);
  int*   epos    = (int*)alloc((size_t)E_TOT * 4);          // 3.4 MB
  int2*  col2    = (int2*)alloc((size_t)E_TOT * 8);         // 6.8 MB
  float4* wtab   = (float4*)alloc((size_t)E_TOT * 16);      // 13.6 MB

  // lifetime aliases (stream-ordered, no concurrent use):
  //   out1 (12.8 MB)  reuses x16   (x16 dead after aggregate-1)
  //   agg2 (51.4 MB)  reuses agg1  (agg1 dead after gemm_mean-1)
  __half* out1 = x16;
  __half* agg2 = agg1;

  const int edge_blocks = (E_TOT + 255) / 256;
  const int node_wave_blocks = (N_NODES + 3) / 4;   // 12500

  hipMemsetAsync(deg, 0, (size_t)N_NODES * 4, stream);
  prep<<<EB + 208, 256, 0, stream>>>(ei, deg, epos, W1, B1p, W2, B2p,
                                     att_s1, att_d1, att_s2, att_d2,
                                     ws1, wd1, ws2, wd2);
  scan_blocks<<<SBLK, 256, 0, stream>>>(deg, row_ptr, bsum);
  scan_tops<<<1, 256, 0, stream>>>(bsum);
  scan_add<<<SBLK, 256, 0, stream>>>(bsum, row_ptr);
  scatter_pos<<<edge_blocks, 256, 0, stream>>>(ei, epos, row_ptr, col2);

  // layer 1
  prep_x<<<node_wave_blocks, 256, 0, stream>>>(x, ws1, wd1, x16, as1, ad1);
  edge_weights<<<edge_blocks, 256, 0, stream>>>(col2, as1, ad1, wtab);
  gat_aggregate_w<4><<<node_wave_blocks, 256, 0, stream>>>(
      x16, wtab, row_ptr, col2, agg1);
  gemm_mean<1024, true><<<MPAD / 64, 256, 0, stream>>>(agg1, B1p, b1, out1);

  // layer 2
  score2<<<node_wave_blocks, 256, 0, stream>>>(out1, ws2, wd2, as2, ad2);
  edge_weights<<<edge_blocks, 256, 0, stream>>>(col2, as2, ad2, wtab);
  gat_aggregate_w<2><<<node_wave_blocks, 256, 0, stream>>>(
      out1, wtab, row_ptr, col2, agg2);
  gemm_mean<512, false><<<MPAD / 64, 256, 0, stream>>>(agg2, B2p, b2, out);
}

// Round 12
// 386.190 us; speedup vs baseline: 1.1600x; 1.0140x over previous
//
#include <hip/hip_runtime.h>
#include <hip/hip_fp16.h>
#include <math.h>

#define N_NODES 50000
#define MPAD    50176              /* padded rows = 784*64 */
#define N_EDGES 800000
#define E_TOT   (N_EDGES + N_NODES)
#define EB      ((E_TOT + 255) / 256)   /* 3321 edge blocks in prep */
#define HEADS   4
#define NEG_SLOPE 0.2f
#define SBLK    ((N_NODES + 255) / 256)  /* 196 scan blocks */

typedef unsigned int u32;
typedef unsigned short u16;
typedef __attribute__((ext_vector_type(8))) _Float16 f16x8;
typedef __attribute__((ext_vector_type(4))) float f32x4;

// =====================================================================
// DUAL-FORM GAT (r18): aggregate PRE-transform features, GEMM after.
// r18 = r17 (best composite, 391.6us) minus two launches:
//   - score2 FUSED into gemm1 epilogue: out1 values are already in
//     registers; round through fp16 so the score dot consumes the exact
//     bits score2 would have re-read from HBM (bit-identical input).
//     Saves 1 launch + 12.8MB re-read.
//   - scan_add ELIMINATED: row_ptr stays block-partial; consumers fold
//     the block offset: f(j) = (j==0) ? 0 : row_ptr[j]+bsum[(j-1)>>8]
//     (scatter_pos per-lane; agg wave-uniform scalar path).
// Aggregates are CLOSED (at gather service ceiling): agg1 555MB/72.3us
// = 7.7TB/s = 12.5 B/cyc/CU; FETCH = 8 XCDs x 25.6MB table compulsory.
// =====================================================================

// ---------------- prep: degree count (+epos) + W permute-casts + w~ ---------

__global__ __launch_bounds__(256) void prep(const int* __restrict__ ei,
                                            int* __restrict__ deg,
                                            int* __restrict__ epos,
                                            const float* __restrict__ W1,
                                            __half* __restrict__ B1,
                                            const float* __restrict__ W2,
                                            __half* __restrict__ B2,
                                            const float* __restrict__ att_s1,
                                            const float* __restrict__ att_d1,
                                            const float* __restrict__ att_s2,
                                            const float* __restrict__ att_d2,
                                            float* __restrict__ ws1,
                                            float* __restrict__ wd1,
                                            float* __restrict__ ws2,
                                            float* __restrict__ wd2) {
  int b = blockIdx.x, tid = threadIdx.x;
  if (b < EB) {
    int e = b * 256 + tid;
    if (e < E_TOT) {
      int dst = (e < N_EDGES) ? ei[N_EDGES + e] : (e - N_EDGES);
      epos[e] = atomicAdd(&deg[dst], 1);
    }
    return;
  }
  if (b < EB + 128) {
    // W1[512x256] -> B1'[j=0..127][k=h*256+c]: B1'[j][h*256+c] = W1[h*128+j][c]
    int k4 = (b - EB) * 256 + tid;                 // 32768 float4
    float4 v = ((const float4*)W1)[k4];
    __half2 h01 = __float22half2_rn(make_float2(v.x, v.y));
    __half2 h23 = __float22half2_rn(make_float2(v.z, v.w));
    uint2 pk = make_uint2(*(u32*)&h01, *(u32*)&h23);
    int r = k4 >> 6, h = r >> 7, j = r & 127;      // r = W1 row, 4 elems/chunk
    ((uint2*)B1)[j * 256 + h * 64 + (k4 & 63)] = pk;
    return;
  }
  if (b < EB + 192) {
    // W2[512x128] -> B2'[j][h*128+c] = W2[h*128+j][c]
    int k4 = (b - EB - 128) * 256 + tid;           // 16384 float4
    float4 v = ((const float4*)W2)[k4];
    __half2 h01 = __float22half2_rn(make_float2(v.x, v.y));
    __half2 h23 = __float22half2_rn(make_float2(v.z, v.w));
    uint2 pk = make_uint2(*(u32*)&h01, *(u32*)&h23);
    int r = k4 >> 5, h = r >> 7, j = r & 127;
    ((uint2*)B2)[j * 128 + h * 32 + (k4 & 31)] = pk;
    return;
  }
  // w~ vectors: w~[h][k] = sum_c att[h][c] * W[h*128+c][k]
  int bw = b - (EB + 192);                         // 0..15
  int h = bw & 3;
  if (bw < 8) {
    const float* att = (bw < 4) ? att_s1 : att_d1;
    float* o = (bw < 4) ? ws1 : wd1;
    int k = tid;                                   // 0..255
    float acc = 0.f;
    for (int c = 0; c < 128; ++c)
      acc = fmaf(att[h * 128 + c], W1[(size_t)(h * 128 + c) * 256 + k], acc);
    o[h * 256 + k] = acc;
  } else {
    const float* att = (bw < 12) ? att_s2 : att_d2;
    float* o = (bw < 12) ? ws2 : wd2;
    if (tid < 128) {
      int k = tid;
      float acc = 0.f;
      for (int c = 0; c < 128; ++c)
        acc = fmaf(att[h * 128 + c], W2[(size_t)(h * 128 + c) * 128 + k], acc);
      o[h * 128 + k] = acc;
    }
  }
}

// ---------------- device-wide degree scan (2 tiny launches) ----------------
// row_ptr holds BLOCK-PARTIAL inclusive sums; bsum holds exclusive block
// offsets. Final value f(j) = (j==0) ? 0 : row_ptr[j] + bsum[(j-1)>>8],
// folded at the consumers (scatter_pos, gat_aggregate_w).

__global__ __launch_bounds__(256) void scan_blocks(const int* __restrict__ deg,
                                                   int* __restrict__ row_ptr,
                                                   int* __restrict__ bsum) {
  __shared__ int sh[256];
  int tid = threadIdx.x;
  int idx = blockIdx.x * 256 + tid;
  int v = (idx < N_NODES) ? deg[idx] : 0;
  sh[tid] = v;
  __syncthreads();
#pragma unroll
  for (int off = 1; off < 256; off <<= 1) {
    int t = (tid >= off) ? sh[tid - off] : 0;
    __syncthreads();
    sh[tid] += t;
    __syncthreads();
  }
  if (idx < N_NODES) row_ptr[idx + 1] = sh[tid];
  if (tid == 255) bsum[blockIdx.x] = sh[255];
}

__global__ __launch_bounds__(256) void scan_tops(int* __restrict__ bsum) {
  __shared__ int sh[256];
  int tid = threadIdx.x;
  int v = (tid < SBLK) ? bsum[tid] : 0;
  sh[tid] = v;
  __syncthreads();
#pragma unroll
  for (int off = 1; off < 256; off <<= 1) {
    int t = (tid >= off) ? sh[tid - off] : 0;
    __syncthreads();
    sh[tid] += t;
    __syncthreads();
  }
  if (tid < SBLK) bsum[tid] = sh[tid] - v;   // exclusive
}

__device__ __forceinline__ float leaky_exp(float a) {
  a = (a >= 0.f) ? a : NEG_SLOPE * a;
  return __expf(a);
}

// ---------------- scatter: no atomics, one packed 8B write per edge --------

__global__ __launch_bounds__(256) void scatter_pos(const int* __restrict__ ei,
                                                   const int* __restrict__ epos,
                                                   const int* __restrict__ row_ptr,
                                                   const int* __restrict__ bsum,
                                                   int2* __restrict__ col2) {
  int e = blockIdx.x * 256 + threadIdx.x;
  if (e >= E_TOT) return;
  int src, dst;
  if (e < N_EDGES) { src = ei[e]; dst = ei[N_EDGES + e]; }
  else             { src = e - N_EDGES; dst = src; }
  int rp = (dst == 0) ? 0 : (row_ptr[dst] + bsum[(dst - 1) >> 8]);
  int slot = rp + epos[e];
  col2[slot] = make_int2(src, dst);
}

// ---------------- edge weights in CSR-slot order (both layers) -------------

__global__ __launch_bounds__(256) void edge_weights(const int2* __restrict__ col2,
                                                    const float* __restrict__ as_,
                                                    const float* __restrict__ ad_,
                                                    float4* __restrict__ wtab) {
  int i = blockIdx.x * 256 + threadIdx.x;
  if (i >= E_TOT) return;
  int2 sd = col2[i];
  float4 a = ((const float4*)as_)[sd.x];
  float4 d = ((const float4*)ad_)[sd.y];
  float4 w;
  w.x = leaky_exp(a.x + d.x);
  w.y = leaky_exp(a.y + d.y);
  w.z = leaky_exp(a.z + d.z);
  w.w = leaky_exp(a.w + d.w);
  wtab[i] = w;
}

// ---------------- prep_x: x fp32->fp16 cast + layer-1 scores ----------------

__global__ __launch_bounds__(256) void prep_x(const float* __restrict__ x,
                                              const float* __restrict__ ws1,
                                              const float* __restrict__ wd1,
                                              __half* __restrict__ x16,
                                              float* __restrict__ as_,
                                              float* __restrict__ ad_) {
  int node = (blockIdx.x * 256 + threadIdx.x) >> 6;
  if (node >= N_NODES) return;
  int lane = threadIdx.x & 63;
  int c4 = lane * 4;
  f32x4 xv = *(const f32x4*)(x + (size_t)node * 256 + c4);
  __half2 h01 = __float22half2_rn(make_float2(xv[0], xv[1]));
  __half2 h23 = __float22half2_rn(make_float2(xv[2], xv[3]));
  uint2 pk = make_uint2(*(u32*)&h01, *(u32*)&h23);
  *(uint2*)(x16 + (size_t)node * 256 + c4) = pk;
  float p[8];
#pragma unroll
  for (int v = 0; v < 4; ++v) {
    f32x4 w = *(const f32x4*)(ws1 + v * 256 + c4);
    p[v] = xv[0] * w[0] + xv[1] * w[1] + xv[2] * w[2] + xv[3] * w[3];
    f32x4 u = *(const f32x4*)(wd1 + v * 256 + c4);
    p[4 + v] = xv[0] * u[0] + xv[1] * u[1] + xv[2] * u[2] + xv[3] * u[3];
  }
#pragma unroll
  for (int k = 0; k < 8; ++k)
#pragma unroll
    for (int m = 1; m < 64; m <<= 1)
      p[k] += __shfl_xor(p[k], m, 64);
  if (lane == 0) {
    *(float4*)(as_ + (size_t)node * 4) = make_float4(p[0], p[1], p[2], p[3]);
    *(float4*)(ad_ + (size_t)node * 4) = make_float4(p[4], p[5], p[6], p[7]);
  }
}

// ---------------- pre-transform aggregation with PRECOMPUTED weights -------
// one wave per dst node; lane holds CPL channels; weights w[e,h] read as a
// sequential 16B broadcast (CSR-slot order). 4-edge unroll (8 regressed:
// service-bound). Plain stores (NT regressed). Row bounds via partial
// row_ptr + bsum fold (wave-uniform scalar path).

template <int CPL>   // 4 -> CHIN=256 (layer 1), 2 -> CHIN=128 (layer 2)
__global__ __launch_bounds__(256) void gat_aggregate_w(
    const __half* __restrict__ tbl, const float4* __restrict__ wtab,
    const int* __restrict__ row_ptr, const int* __restrict__ bsum,
    const int2* __restrict__ col2, __half* __restrict__ agg) {
  constexpr int CHIN = CPL * 64;
  const int* colx = (const int*)col2;               // .x at index 2*i
  int node = (blockIdx.x * 256 + threadIdx.x) >> 6;   // wave-uniform
  if (node >= N_NODES) return;
  int lane = threadIdx.x & 63, cb = lane * CPL;
  const __half* tb = tbl + cb;
  int s = (node == 0)
              ? 0
              : __builtin_amdgcn_readfirstlane(row_ptr[node] +
                                               bsum[(node - 1) >> 8]);
  int e = __builtin_amdgcn_readfirstlane(row_ptr[node + 1] + bsum[node >> 8]);

  float acc[4][CPL];
#pragma unroll
  for (int h = 0; h < 4; ++h)
#pragma unroll
    for (int c = 0; c < CPL; ++c) acc[h][c] = 0.f;
  float den[4] = {0.f, 0.f, 0.f, 0.f};

  auto accum = [&](uint2 q, float4 w) {
    float wv[4] = {w.x, w.y, w.z, w.w};
#pragma unroll
    for (int h = 0; h < 4; ++h) den[h] += wv[h];
    float f[CPL];
    float2 f0 = __half22float2(*(__half2*)&q.x);
    f[0] = f0.x; f[1] = f0.y;
    if (CPL == 4) {
      float2 f1 = __half22float2(*(__half2*)&q.y);
      f[2] = f1.x; f[3] = f1.y;
    }
#pragma unroll
    for (int h = 0; h < 4; ++h)
#pragma unroll
      for (int c = 0; c < CPL; ++c)
        acc[h][c] = fmaf(wv[h], f[c], acc[h][c]);
  };
  auto loadq = [&](int src) -> uint2 {
    if (CPL == 4) return *(const uint2*)(tb + (size_t)src * CHIN);
    uint2 r; r.x = *(const u32*)(tb + (size_t)src * CHIN); r.y = 0;
    return r;
  };

  int i = s;
  for (; i + 4 <= e; i += 4) {
    int s0 = __builtin_amdgcn_readfirstlane(colx[2 * i]);
    int s1 = __builtin_amdgcn_readfirstlane(colx[2 * i + 2]);
    int s2 = __builtin_amdgcn_readfirstlane(colx[2 * i + 4]);
    int s3 = __builtin_amdgcn_readfirstlane(colx[2 * i + 6]);
    float4 w0 = wtab[i],     w1 = wtab[i + 1];
    float4 w2 = wtab[i + 2], w3 = wtab[i + 3];
    uint2 q0 = loadq(s0), q1 = loadq(s1), q2 = loadq(s2), q3 = loadq(s3);
    accum(q0, w0); accum(q1, w1); accum(q2, w2); accum(q3, w3);
  }
  for (; i < e; ++i) {
    int s0 = __builtin_amdgcn_readfirstlane(colx[2 * i]);
    float4 w0 = wtab[i];
    accum(loadq(s0), w0);
  }

#pragma unroll
  for (int h = 0; h < 4; ++h) {
    float inv = 1.f / (den[h] + 1e-16f);
    if (CPL == 4) {
      __half2 o0 = __float22half2_rn(make_float2(acc[h][0] * inv, acc[h][1] * inv));
      __half2 o1 = __float22half2_rn(make_float2(acc[h][2] * inv, acc[h][3] * inv));
      *(uint2*)(agg + (size_t)node * 4 * CHIN + h * CHIN + cb) =
          make_uint2(*(u32*)&o0, *(u32*)&o1);
    } else {
      __half2 o0 = __float22half2_rn(make_float2(acc[h][0] * inv, acc[h][1] * inv));
      *(u32*)(agg + (size_t)node * 4 * CHIN + h * CHIN + cb) = *(u32*)&o0;
    }
  }
}

// ---------------- post-aggregation GEMM: out = 0.25 * A @ B'^T + bias ------
// A[MPAD x K] fp16 (agg, head-concat K), B'[128 x K] fp16, out [MPAD x 128].
// 64x128 tile, 256 thr = 4 waves (2 row x 2 col), acc[2][4], grid 784.
// SCORES: fused layer-2 score epilogue. Each lane rounds its out value
// through fp16 (bit-identical to what score2 read from HBM), dots with
// ws2/wd2 over its 4 cols, 16-lane shfl-tree reduce, LDS-combine across
// the two col-waves -> as2/ad2. Saves the score2 launch + 12.8MB re-read.

#define GLD16(gp, lp)                                                          \
  __builtin_amdgcn_global_load_lds(                                            \
      (const __attribute__((address_space(1))) u32*)(gp),                      \
      (__attribute__((address_space(3))) u32*)(lp), 16, 0, 0)

template <int K, bool HALF_OUT, bool SCORES>
__global__ __launch_bounds__(256, 4) void gemm_mean(
    const __half* __restrict__ A, const __half* __restrict__ Bm,
    const float* __restrict__ bias, void* __restrict__ outv,
    const float* __restrict__ ws2, const float* __restrict__ wd2,
    float* __restrict__ as2g, float* __restrict__ ad2g) {
  __shared__ u16 sA[64 * 32];    // 4 KB
  __shared__ u16 sB[128 * 32];   // 8 KB
  __shared__ float sS[2][64][4]; // 2 KB (score partials, col-wave split)
  __shared__ float sD[2][64][4]; // 2 KB
  const int tid = threadIdx.x, lane = tid & 63, wave = tid >> 6;  // 0..3
  const int m0 = blockIdx.x * 64;
  const int wm = (wave >> 1) * 32, wn = (wave & 1) * 64;
  const int t = lane & 15, quad = lane >> 4;

  f32x4 acc[2][4];
#pragma unroll
  for (int i = 0; i < 2; i++)
#pragma unroll
    for (int j = 0; j < 4; j++) acc[i][j] = (f32x4){0.f, 0.f, 0.f, 0.f};

  const char* gpA; u32 offA;
  {
    int row = tid >> 2, w16 = tid & 3;  // 256 chunks: 64 rows x 4
    gpA = (const char*)A + ((size_t)(m0 + row) * K) * 2 + w16 * 16;
    offA = (u32)tid * 16;
  }
  const char* gpB[2]; u32 offB[2];
#pragma unroll
  for (int r = 0; r < 2; ++r) {
    int c = tid + r * 256;              // 512 chunks: 128 rows x 4
    int row = c >> 2, w16 = c & 3;
    gpB[r] = (const char*)Bm + ((size_t)row * K) * 2 + w16 * 16;
    offB[r] = (u32)c * 16;
  }

  for (int k0 = 0; k0 < K; k0 += 32) {
    __syncthreads();
    GLD16(gpA, (char*)sA + offA); gpA += 64;
#pragma unroll
    for (int r = 0; r < 2; ++r) { GLD16(gpB[r], (char*)sB + offB[r]); gpB[r] += 64; }
    __syncthreads();

    f16x8 a[2], b[4];
#pragma unroll
    for (int i = 0; i < 2; ++i)
      a[i] = *(const f16x8*)&sA[(wm + t + i * 16) * 32 + quad * 8];
#pragma unroll
    for (int j = 0; j < 4; ++j)
      b[j] = *(const f16x8*)&sB[(wn + t + j * 16) * 32 + quad * 8];
#pragma unroll
    for (int i = 0; i < 2; ++i)
#pragma unroll
      for (int j = 0; j < 4; ++j)
        acc[i][j] = __builtin_amdgcn_mfma_f32_16x16x32_f16(a[i], b[j], acc[i][j], 0, 0, 0);
  }

  float bv[4];
#pragma unroll
  for (int j = 0; j < 4; ++j) bv[j] = bias[wn + j * 16 + t];

  float ws2v[4][4], wd2v[4][4];
  if constexpr (SCORES) {
#pragma unroll
    for (int h = 0; h < 4; ++h)
#pragma unroll
      for (int j = 0; j < 4; ++j) {
        int n = wn + j * 16 + t;
        ws2v[h][j] = ws2[h * 128 + n];
        wd2v[h][j] = wd2[h * 128 + n];
      }
  }

#pragma unroll
  for (int i = 0; i < 2; ++i)
#pragma unroll
    for (int r = 0; r < 4; ++r) {
      int m = m0 + wm + i * 16 + quad * 4 + r;   // C/D: col=lane&15, row=quad*4+reg
      float vj[4];
#pragma unroll
      for (int j = 0; j < 4; ++j) {
        float v = 0.25f * acc[i][j][r] + bv[j];
        __half hv = __float2half(v);
        vj[j] = __half2float(hv);                // fp16-rounded (bit-exact feed)
        if (m < N_NODES) {
          int n = wn + j * 16 + t;
          if (HALF_OUT) ((__half*)outv)[(size_t)m * 128 + n] = hv;
          else          ((float*)outv)[(size_t)m * 128 + n] = v;
        }
      }
      if constexpr (SCORES) {
        float ps[4], pd[4];
#pragma unroll
        for (int h = 0; h < 4; ++h) {
          ps[h] = vj[0] * ws2v[h][0] + vj[1] * ws2v[h][1] +
                  vj[2] * ws2v[h][2] + vj[3] * ws2v[h][3];
          pd[h] = vj[0] * wd2v[h][0] + vj[1] * wd2v[h][1] +
                  vj[2] * wd2v[h][2] + vj[3] * wd2v[h][3];
        }
#pragma unroll
        for (int mask = 1; mask < 16; mask <<= 1)
#pragma unroll
          for (int h = 0; h < 4; ++h) {
            ps[h] += __shfl_xor(ps[h], mask, 64);
            pd[h] += __shfl_xor(pd[h], mask, 64);
          }
        if (t == 0) {
          int rl = wm + i * 16 + quad * 4 + r;   // 0..63
#pragma unroll
          for (int h = 0; h < 4; ++h) {
            sS[wave & 1][rl][h] = ps[h];
            sD[wave & 1][rl][h] = pd[h];
          }
        }
      }
    }

  if constexpr (SCORES) {
    __syncthreads();
    int row = tid >> 2, h = tid & 3;             // 256 thr -> 64 rows x 4 h
    int gm = m0 + row;
    if (gm < N_NODES) {
      as2g[gm * 4 + h] = sS[0][row][h] + sS[1][row][h];
      ad2g[gm * 4 + h] = sD[0][row][h] + sD[1][row][h];
    }
  }
}

// ---------------- launch ----------------

extern "C" void kernel_launch(void* const* d_in, const int* in_sizes, int n_in,
                              void* d_out, int out_size, void* d_ws, size_t ws_size,
                              hipStream_t stream) {
  const float* x      = (const float*)d_in[0];
  const int*   ei     = (const int*)  d_in[1];
  const float* W1     = (const float*)d_in[2];
  const float* att_s1 = (const float*)d_in[3];
  const float* att_d1 = (const float*)d_in[4];
  const float* b1     = (const float*)d_in[5];
  const float* W2     = (const float*)d_in[6];
  const float* att_s2 = (const float*)d_in[7];
  const float* att_d2 = (const float*)d_in[8];
  const float* b2     = (const float*)d_in[9];
  float* out = (float*)d_out;

  char* ws = (char*)d_ws;
  size_t off = 0;
  auto alloc = [&](size_t bytes) -> void* {
    void* p = ws + off;
    off += (bytes + 255) & ~(size_t)255;
    return p;
  };
  __half* x16  = (__half*)alloc((size_t)MPAD * 256 * 2);    // 25.7 MB
  __half* agg1 = (__half*)alloc((size_t)MPAD * 1024 * 2);   // 102.8 MB
  __half* B1p  = (__half*)alloc((size_t)128 * 1024 * 2);
  __half* B2p  = (__half*)alloc((size_t)128 * 512 * 2);
  float* ws1 = (float*)alloc(4 * 256 * 4);
  float* wd1 = (float*)alloc(4 * 256 * 4);
  float* ws2 = (float*)alloc(4 * 128 * 4);
  float* wd2 = (float*)alloc(4 * 128 * 4);
  float* as1 = (float*)alloc((size_t)N_NODES * 4 * 4);
  float* ad1 = (float*)alloc((size_t)N_NODES * 4 * 4);
  float* as2 = (float*)alloc((size_t)N_NODES * 4 * 4);
  float* ad2 = (float*)alloc((size_t)N_NODES * 4 * 4);
  int*   row_ptr = (int*)alloc((size_t)(N_NODES + 1) * 4);
  int*   deg     = (int*)alloc((size_t)N_NODES * 4);
  int*   bsum    = (int*)alloc((size_t)256 * 4);
  int*   epos    = (int*)alloc((size_t)E_TOT * 4);          // 3.4 MB
  int2*  col2    = (int2*)alloc((size_t)E_TOT * 8);         // 6.8 MB
  float4* wtab   = (float4*)alloc((size_t)E_TOT * 16);      // 13.6 MB

  // lifetime aliases (stream-ordered, no concurrent use):
  //   out1 (12.8 MB)  reuses x16   (x16 dead after aggregate-1)
  //   agg2 (51.4 MB)  reuses agg1  (agg1 dead after gemm_mean-1)
  __half* out1 = x16;
  __half* agg2 = agg1;

  const int edge_blocks = (E_TOT + 255) / 256;
  const int node_wave_blocks = (N_NODES + 3) / 4;   // 12500

  hipMemsetAsync(deg, 0, (size_t)N_NODES * 4, stream);
  prep<<<EB + 208, 256, 0, stream>>>(ei, deg, epos, W1, B1p, W2, B2p,
                                     att_s1, att_d1, att_s2, att_d2,
                                     ws1, wd1, ws2, wd2);
  scan_blocks<<<SBLK, 256, 0, stream>>>(deg, row_ptr, bsum);
  scan_tops<<<1, 256, 0, stream>>>(bsum);
  scatter_pos<<<edge_blocks, 256, 0, stream>>>(ei, epos, row_ptr, bsum, col2);

  // layer 1
  prep_x<<<node_wave_blocks, 256, 0, stream>>>(x, ws1, wd1, x16, as1, ad1);
  edge_weights<<<edge_blocks, 256, 0, stream>>>(col2, as1, ad1, wtab);
  gat_aggregate_w<4><<<node_wave_blocks, 256, 0, stream>>>(
      x16, wtab, row_ptr, bsum, col2, agg1);
  gemm_mean<1024, true, true><<<MPAD / 64, 256, 0, stream>>>(
      agg1, B1p, b1, out1, ws2, wd2, as2, ad2);

  // layer 2 (scores already produced by gemm1's fused epilogue)
  edge_weights<<<edge_blocks, 256, 0, stream>>>(col2, as2, ad2, wtab);
  gat_aggregate_w<2><<<node_wave_blocks, 256, 0, stream>>>(
      out1, wtab, row_ptr, bsum, col2, agg2);
  gemm_mean<512, false, false><<<MPAD / 64, 256, 0, stream>>>(
      agg2, B2p, b2, out, nullptr, nullptr, nullptr, nullptr);
}

// Round 13
// 373.887 us; speedup vs baseline: 1.1982x; 1.0329x over previous
//
#include <hip/hip_runtime.h>
#include <hip/hip_fp16.h>
#include <math.h>

#define N_NODES 50000
#define MPAD    50176              /* padded rows = 784*64 */
#define N_EDGES 800000
#define E_TOT   (N_EDGES + N_NODES)
#define EB      ((E_TOT + 255) / 256)   /* 3321 edge blocks in prep */
#define HEADS   4
#define NEG_SLOPE 0.2f
#define SBLK    ((N_NODES + 255) / 256)  /* 196 scan blocks */

typedef unsigned int u32;
typedef unsigned short u16;
typedef __attribute__((ext_vector_type(8))) _Float16 f16x8;
typedef __attribute__((ext_vector_type(4))) float f32x4;

// =====================================================================
// DUAL-FORM GAT (r19): aggregate PRE-transform features, GEMM after.
// r19 = r18 with the agg codegen regression fixed. r18's bsum-fold
// INSIDE gat_aggregate_w defeated scalarization (SGPR 64->32, VGPR
// 24->32, VALUBusy 39->49%, 72.2->77.7us): the extra loads + node==0
// branch in the bounds path pushed the scalar row/col path to VALU.
// Now: row_ptr finalization rides as 196 extra blocks on scatter_pos's
// grid (multi-role-block pattern), writing a SEPARATE row_ptrF (no
// race with edge blocks reading partial row_ptr). Aggregate takes
// row_ptrF with the exact r17 body (72.2us codegen). score2 fusion
// into gemm1 epilogue kept (clean win).
// =====================================================================

// ---------------- prep: degree count (+epos) + W permute-casts + w~ ---------

__global__ __launch_bounds__(256) void prep(const int* __restrict__ ei,
                                            int* __restrict__ deg,
                                            int* __restrict__ epos,
                                            const float* __restrict__ W1,
                                            __half* __restrict__ B1,
                                            const float* __restrict__ W2,
                                            __half* __restrict__ B2,
                                            const float* __restrict__ att_s1,
                                            const float* __restrict__ att_d1,
                                            const float* __restrict__ att_s2,
                                            const float* __restrict__ att_d2,
                                            float* __restrict__ ws1,
                                            float* __restrict__ wd1,
                                            float* __restrict__ ws2,
                                            float* __restrict__ wd2) {
  int b = blockIdx.x, tid = threadIdx.x;
  if (b < EB) {
    int e = b * 256 + tid;
    if (e < E_TOT) {
      int dst = (e < N_EDGES) ? ei[N_EDGES + e] : (e - N_EDGES);
      epos[e] = atomicAdd(&deg[dst], 1);
    }
    return;
  }
  if (b < EB + 128) {
    // W1[512x256] -> B1'[j=0..127][k=h*256+c]: B1'[j][h*256+c] = W1[h*128+j][c]
    int k4 = (b - EB) * 256 + tid;                 // 32768 float4
    float4 v = ((const float4*)W1)[k4];
    __half2 h01 = __float22half2_rn(make_float2(v.x, v.y));
    __half2 h23 = __float22half2_rn(make_float2(v.z, v.w));
    uint2 pk = make_uint2(*(u32*)&h01, *(u32*)&h23);
    int r = k4 >> 6, h = r >> 7, j = r & 127;      // r = W1 row, 4 elems/chunk
    ((uint2*)B1)[j * 256 + h * 64 + (k4 & 63)] = pk;
    return;
  }
  if (b < EB + 192) {
    // W2[512x128] -> B2'[j][h*128+c] = W2[h*128+j][c]
    int k4 = (b - EB - 128) * 256 + tid;           // 16384 float4
    float4 v = ((const float4*)W2)[k4];
    __half2 h01 = __float22half2_rn(make_float2(v.x, v.y));
    __half2 h23 = __float22half2_rn(make_float2(v.z, v.w));
    uint2 pk = make_uint2(*(u32*)&h01, *(u32*)&h23);
    int r = k4 >> 5, h = r >> 7, j = r & 127;
    ((uint2*)B2)[j * 128 + h * 32 + (k4 & 31)] = pk;
    return;
  }
  // w~ vectors: w~[h][k] = sum_c att[h][c] * W[h*128+c][k]
  int bw = b - (EB + 192);                         // 0..15
  int h = bw & 3;
  if (bw < 8) {
    const float* att = (bw < 4) ? att_s1 : att_d1;
    float* o = (bw < 4) ? ws1 : wd1;
    int k = tid;                                   // 0..255
    float acc = 0.f;
    for (int c = 0; c < 128; ++c)
      acc = fmaf(att[h * 128 + c], W1[(size_t)(h * 128 + c) * 256 + k], acc);
    o[h * 256 + k] = acc;
  } else {
    const float* att = (bw < 12) ? att_s2 : att_d2;
    float* o = (bw < 12) ? ws2 : wd2;
    if (tid < 128) {
      int k = tid;
      float acc = 0.f;
      for (int c = 0; c < 128; ++c)
        acc = fmaf(att[h * 128 + c], W2[(size_t)(h * 128 + c) * 128 + k], acc);
      o[h * 128 + k] = acc;
    }
  }
}

// ---------------- device-wide degree scan (2 tiny launches) ----------------
// row_ptr holds BLOCK-PARTIAL inclusive sums; bsum exclusive block offsets.
// Finalization into row_ptrF rides on scatter_pos's grid (below).

__global__ __launch_bounds__(256) void scan_blocks(const int* __restrict__ deg,
                                                   int* __restrict__ row_ptr,
                                                   int* __restrict__ bsum) {
  __shared__ int sh[256];
  int tid = threadIdx.x;
  int idx = blockIdx.x * 256 + tid;
  int v = (idx < N_NODES) ? deg[idx] : 0;
  sh[tid] = v;
  __syncthreads();
#pragma unroll
  for (int off = 1; off < 256; off <<= 1) {
    int t = (tid >= off) ? sh[tid - off] : 0;
    __syncthreads();
    sh[tid] += t;
    __syncthreads();
  }
  if (idx < N_NODES) row_ptr[idx + 1] = sh[tid];
  if (tid == 255) bsum[blockIdx.x] = sh[255];
}

__global__ __launch_bounds__(256) void scan_tops(int* __restrict__ bsum) {
  __shared__ int sh[256];
  int tid = threadIdx.x;
  int v = (tid < SBLK) ? bsum[tid] : 0;
  sh[tid] = v;
  __syncthreads();
#pragma unroll
  for (int off = 1; off < 256; off <<= 1) {
    int t = (tid >= off) ? sh[tid - off] : 0;
    __syncthreads();
    sh[tid] += t;
    __syncthreads();
  }
  if (tid < SBLK) bsum[tid] = sh[tid] - v;   // exclusive
}

__device__ __forceinline__ float leaky_exp(float a) {
  a = (a >= 0.f) ? a : NEG_SLOPE * a;
  return __expf(a);
}

// ---------------- scatter + row_ptr finalize (multi-role grid) -------------
// Blocks [0, EB): one packed 8B write per edge, slot from partial+bsum.
// Blocks [EB, EB+SBLK): row_ptrF[idx+1] = row_ptr[idx+1] + bsum[idx>>8]
// (separate output array -> no race with edge blocks reading partials).

__global__ __launch_bounds__(256) void scatter_pos(const int* __restrict__ ei,
                                                   const int* __restrict__ epos,
                                                   const int* __restrict__ row_ptr,
                                                   const int* __restrict__ bsum,
                                                   int2* __restrict__ col2,
                                                   int* __restrict__ row_ptrF) {
  int b = blockIdx.x, tid = threadIdx.x;
  if (b >= EB) {
    int idx = (b - EB) * 256 + tid;
    if (idx == 0) row_ptrF[0] = 0;
    if (idx < N_NODES) row_ptrF[idx + 1] = row_ptr[idx + 1] + bsum[idx >> 8];
    return;
  }
  int e = b * 256 + tid;
  if (e >= E_TOT) return;
  int src, dst;
  if (e < N_EDGES) { src = ei[e]; dst = ei[N_EDGES + e]; }
  else             { src = e - N_EDGES; dst = src; }
  int rp = (dst == 0) ? 0 : (row_ptr[dst] + bsum[(dst - 1) >> 8]);
  int slot = rp + epos[e];
  col2[slot] = make_int2(src, dst);
}

// ---------------- edge weights in CSR-slot order (both layers) -------------

__global__ __launch_bounds__(256) void edge_weights(const int2* __restrict__ col2,
                                                    const float* __restrict__ as_,
                                                    const float* __restrict__ ad_,
                                                    float4* __restrict__ wtab) {
  int i = blockIdx.x * 256 + threadIdx.x;
  if (i >= E_TOT) return;
  int2 sd = col2[i];
  float4 a = ((const float4*)as_)[sd.x];
  float4 d = ((const float4*)ad_)[sd.y];
  float4 w;
  w.x = leaky_exp(a.x + d.x);
  w.y = leaky_exp(a.y + d.y);
  w.z = leaky_exp(a.z + d.z);
  w.w = leaky_exp(a.w + d.w);
  wtab[i] = w;
}

// ---------------- prep_x: x fp32->fp16 cast + layer-1 scores ----------------

__global__ __launch_bounds__(256) void prep_x(const float* __restrict__ x,
                                              const float* __restrict__ ws1,
                                              const float* __restrict__ wd1,
                                              __half* __restrict__ x16,
                                              float* __restrict__ as_,
                                              float* __restrict__ ad_) {
  int node = (blockIdx.x * 256 + threadIdx.x) >> 6;
  if (node >= N_NODES) return;
  int lane = threadIdx.x & 63;
  int c4 = lane * 4;
  f32x4 xv = *(const f32x4*)(x + (size_t)node * 256 + c4);
  __half2 h01 = __float22half2_rn(make_float2(xv[0], xv[1]));
  __half2 h23 = __float22half2_rn(make_float2(xv[2], xv[3]));
  uint2 pk = make_uint2(*(u32*)&h01, *(u32*)&h23);
  *(uint2*)(x16 + (size_t)node * 256 + c4) = pk;
  float p[8];
#pragma unroll
  for (int v = 0; v < 4; ++v) {
    f32x4 w = *(const f32x4*)(ws1 + v * 256 + c4);
    p[v] = xv[0] * w[0] + xv[1] * w[1] + xv[2] * w[2] + xv[3] * w[3];
    f32x4 u = *(const f32x4*)(wd1 + v * 256 + c4);
    p[4 + v] = xv[0] * u[0] + xv[1] * u[1] + xv[2] * u[2] + xv[3] * u[3];
  }
#pragma unroll
  for (int k = 0; k < 8; ++k)
#pragma unroll
    for (int m = 1; m < 64; m <<= 1)
      p[k] += __shfl_xor(p[k], m, 64);
  if (lane == 0) {
    *(float4*)(as_ + (size_t)node * 4) = make_float4(p[0], p[1], p[2], p[3]);
    *(float4*)(ad_ + (size_t)node * 4) = make_float4(p[4], p[5], p[6], p[7]);
  }
}

// ---------------- pre-transform aggregation with PRECOMPUTED weights -------
// EXACT r17 body (72.2us codegen: scalar row bounds, SGPR col path).
// one wave per dst node; lane holds CPL channels; weights w[e,h] read as a
// sequential 16B broadcast (CSR-slot order). 4-edge unroll; plain stores.

template <int CPL>   // 4 -> CHIN=256 (layer 1), 2 -> CHIN=128 (layer 2)
__global__ __launch_bounds__(256) void gat_aggregate_w(
    const __half* __restrict__ tbl, const float4* __restrict__ wtab,
    const int* __restrict__ row_ptr, const int2* __restrict__ col2,
    __half* __restrict__ agg) {
  constexpr int CHIN = CPL * 64;
  const int* colx = (const int*)col2;               // .x at index 2*i
  int node = (blockIdx.x * 256 + threadIdx.x) >> 6;   // wave-uniform
  if (node >= N_NODES) return;
  int lane = threadIdx.x & 63, cb = lane * CPL;
  const __half* tb = tbl + cb;
  int s = __builtin_amdgcn_readfirstlane(row_ptr[node]);
  int e = __builtin_amdgcn_readfirstlane(row_ptr[node + 1]);

  float acc[4][CPL];
#pragma unroll
  for (int h = 0; h < 4; ++h)
#pragma unroll
    for (int c = 0; c < CPL; ++c) acc[h][c] = 0.f;
  float den[4] = {0.f, 0.f, 0.f, 0.f};

  auto accum = [&](uint2 q, float4 w) {
    float wv[4] = {w.x, w.y, w.z, w.w};
#pragma unroll
    for (int h = 0; h < 4; ++h) den[h] += wv[h];
    float f[CPL];
    float2 f0 = __half22float2(*(__half2*)&q.x);
    f[0] = f0.x; f[1] = f0.y;
    if (CPL == 4) {
      float2 f1 = __half22float2(*(__half2*)&q.y);
      f[2] = f1.x; f[3] = f1.y;
    }
#pragma unroll
    for (int h = 0; h < 4; ++h)
#pragma unroll
      for (int c = 0; c < CPL; ++c)
        acc[h][c] = fmaf(wv[h], f[c], acc[h][c]);
  };
  auto loadq = [&](int src) -> uint2 {
    if (CPL == 4) return *(const uint2*)(tb + (size_t)src * CHIN);
    uint2 r; r.x = *(const u32*)(tb + (size_t)src * CHIN); r.y = 0;
    return r;
  };

  int i = s;
  for (; i + 4 <= e; i += 4) {
    int s0 = __builtin_amdgcn_readfirstlane(colx[2 * i]);
    int s1 = __builtin_amdgcn_readfirstlane(colx[2 * i + 2]);
    int s2 = __builtin_amdgcn_readfirstlane(colx[2 * i + 4]);
    int s3 = __builtin_amdgcn_readfirstlane(colx[2 * i + 6]);
    float4 w0 = wtab[i],     w1 = wtab[i + 1];
    float4 w2 = wtab[i + 2], w3 = wtab[i + 3];
    uint2 q0 = loadq(s0), q1 = loadq(s1), q2 = loadq(s2), q3 = loadq(s3);
    accum(q0, w0); accum(q1, w1); accum(q2, w2); accum(q3, w3);
  }
  for (; i < e; ++i) {
    int s0 = __builtin_amdgcn_readfirstlane(colx[2 * i]);
    float4 w0 = wtab[i];
    accum(loadq(s0), w0);
  }

#pragma unroll
  for (int h = 0; h < 4; ++h) {
    float inv = 1.f / (den[h] + 1e-16f);
    if (CPL == 4) {
      __half2 o0 = __float22half2_rn(make_float2(acc[h][0] * inv, acc[h][1] * inv));
      __half2 o1 = __float22half2_rn(make_float2(acc[h][2] * inv, acc[h][3] * inv));
      *(uint2*)(agg + (size_t)node * 4 * CHIN + h * CHIN + cb) =
          make_uint2(*(u32*)&o0, *(u32*)&o1);
    } else {
      __half2 o0 = __float22half2_rn(make_float2(acc[h][0] * inv, acc[h][1] * inv));
      *(u32*)(agg + (size_t)node * 4 * CHIN + h * CHIN + cb) = *(u32*)&o0;
    }
  }
}

// ---------------- post-aggregation GEMM: out = 0.25 * A @ B'^T + bias ------
// A[MPAD x K] fp16 (agg, head-concat K), B'[128 x K] fp16, out [MPAD x 128].
// 64x128 tile, 256 thr = 4 waves (2 row x 2 col), acc[2][4], grid 784.
// SCORES: fused layer-2 score epilogue (fp16-rounded, bit-exact feed).

#define GLD16(gp, lp)                                                          \
  __builtin_amdgcn_global_load_lds(                                            \
      (const __attribute__((address_space(1))) u32*)(gp),                      \
      (__attribute__((address_space(3))) u32*)(lp), 16, 0, 0)

template <int K, bool HALF_OUT, bool SCORES>
__global__ __launch_bounds__(256, 4) void gemm_mean(
    const __half* __restrict__ A, const __half* __restrict__ Bm,
    const float* __restrict__ bias, void* __restrict__ outv,
    const float* __restrict__ ws2, const float* __restrict__ wd2,
    float* __restrict__ as2g, float* __restrict__ ad2g) {
  __shared__ u16 sA[64 * 32];    // 4 KB
  __shared__ u16 sB[128 * 32];   // 8 KB
  __shared__ float sS[2][64][4]; // 2 KB (score partials, col-wave split)
  __shared__ float sD[2][64][4]; // 2 KB
  const int tid = threadIdx.x, lane = tid & 63, wave = tid >> 6;  // 0..3
  const int m0 = blockIdx.x * 64;
  const int wm = (wave >> 1) * 32, wn = (wave & 1) * 64;
  const int t = lane & 15, quad = lane >> 4;

  f32x4 acc[2][4];
#pragma unroll
  for (int i = 0; i < 2; i++)
#pragma unroll
    for (int j = 0; j < 4; j++) acc[i][j] = (f32x4){0.f, 0.f, 0.f, 0.f};

  const char* gpA; u32 offA;
  {
    int row = tid >> 2, w16 = tid & 3;  // 256 chunks: 64 rows x 4
    gpA = (const char*)A + ((size_t)(m0 + row) * K) * 2 + w16 * 16;
    offA = (u32)tid * 16;
  }
  const char* gpB[2]; u32 offB[2];
#pragma unroll
  for (int r = 0; r < 2; ++r) {
    int c = tid + r * 256;              // 512 chunks: 128 rows x 4
    int row = c >> 2, w16 = c & 3;
    gpB[r] = (const char*)Bm + ((size_t)row * K) * 2 + w16 * 16;
    offB[r] = (u32)c * 16;
  }

  for (int k0 = 0; k0 < K; k0 += 32) {
    __syncthreads();
    GLD16(gpA, (char*)sA + offA); gpA += 64;
#pragma unroll
    for (int r = 0; r < 2; ++r) { GLD16(gpB[r], (char*)sB + offB[r]); gpB[r] += 64; }
    __syncthreads();

    f16x8 a[2], b[4];
#pragma unroll
    for (int i = 0; i < 2; ++i)
      a[i] = *(const f16x8*)&sA[(wm + t + i * 16) * 32 + quad * 8];
#pragma unroll
    for (int j = 0; j < 4; ++j)
      b[j] = *(const f16x8*)&sB[(wn + t + j * 16) * 32 + quad * 8];
#pragma unroll
    for (int i = 0; i < 2; ++i)
#pragma unroll
      for (int j = 0; j < 4; ++j)
        acc[i][j] = __builtin_amdgcn_mfma_f32_16x16x32_f16(a[i], b[j], acc[i][j], 0, 0, 0);
  }

  float bv[4];
#pragma unroll
  for (int j = 0; j < 4; ++j) bv[j] = bias[wn + j * 16 + t];

  float ws2v[4][4], wd2v[4][4];
  if constexpr (SCORES) {
#pragma unroll
    for (int h = 0; h < 4; ++h)
#pragma unroll
      for (int j = 0; j < 4; ++j) {
        int n = wn + j * 16 + t;
        ws2v[h][j] = ws2[h * 128 + n];
        wd2v[h][j] = wd2[h * 128 + n];
      }
  }

#pragma unroll
  for (int i = 0; i < 2; ++i)
#pragma unroll
    for (int r = 0; r < 4; ++r) {
      int m = m0 + wm + i * 16 + quad * 4 + r;   // C/D: col=lane&15, row=quad*4+reg
      float vj[4];
#pragma unroll
      for (int j = 0; j < 4; ++j) {
        float v = 0.25f * acc[i][j][r] + bv[j];
        __half hv = __float2half(v);
        vj[j] = __half2float(hv);                // fp16-rounded (bit-exact feed)
        if (m < N_NODES) {
          int n = wn + j * 16 + t;
          if (HALF_OUT) ((__half*)outv)[(size_t)m * 128 + n] = hv;
          else          ((float*)outv)[(size_t)m * 128 + n] = v;
        }
      }
      if constexpr (SCORES) {
        float ps[4], pd[4];
#pragma unroll
        for (int h = 0; h < 4; ++h) {
          ps[h] = vj[0] * ws2v[h][0] + vj[1] * ws2v[h][1] +
                  vj[2] * ws2v[h][2] + vj[3] * ws2v[h][3];
          pd[h] = vj[0] * wd2v[h][0] + vj[1] * wd2v[h][1] +
                  vj[2] * wd2v[h][2] + vj[3] * wd2v[h][3];
        }
#pragma unroll
        for (int mask = 1; mask < 16; mask <<= 1)
#pragma unroll
          for (int h = 0; h < 4; ++h) {
            ps[h] += __shfl_xor(ps[h], mask, 64);
            pd[h] += __shfl_xor(pd[h], mask, 64);
          }
        if (t == 0) {
          int rl = wm + i * 16 + quad * 4 + r;   // 0..63
#pragma unroll
          for (int h = 0; h < 4; ++h) {
            sS[wave & 1][rl][h] = ps[h];
            sD[wave & 1][rl][h] = pd[h];
          }
        }
      }
    }

  if constexpr (SCORES) {
    __syncthreads();
    int row = tid >> 2, h = tid & 3;             // 256 thr -> 64 rows x 4 h
    int gm = m0 + row;
    if (gm < N_NODES) {
      as2g[gm * 4 + h] = sS[0][row][h] + sS[1][row][h];
      ad2g[gm * 4 + h] = sD[0][row][h] + sD[1][row][h];
    }
  }
}

// ---------------- launch ----------------

extern "C" void kernel_launch(void* const* d_in, const int* in_sizes, int n_in,
                              void* d_out, int out_size, void* d_ws, size_t ws_size,
                              hipStream_t stream) {
  const float* x      = (const float*)d_in[0];
  const int*   ei     = (const int*)  d_in[1];
  const float* W1     = (const float*)d_in[2];
  const float* att_s1 = (const float*)d_in[3];
  const float* att_d1 = (const float*)d_in[4];
  const float* b1     = (const float*)d_in[5];
  const float* W2     = (const float*)d_in[6];
  const float* att_s2 = (const float*)d_in[7];
  const float* att_d2 = (const float*)d_in[8];
  const float* b2     = (const float*)d_in[9];
  float* out = (float*)d_out;

  char* ws = (char*)d_ws;
  size_t off = 0;
  auto alloc = [&](size_t bytes) -> void* {
    void* p = ws + off;
    off += (bytes + 255) & ~(size_t)255;
    return p;
  };
  __half* x16  = (__half*)alloc((size_t)MPAD * 256 * 2);    // 25.7 MB
  __half* agg1 = (__half*)alloc((size_t)MPAD * 1024 * 2);   // 102.8 MB
  __half* B1p  = (__half*)alloc((size_t)128 * 1024 * 2);
  __half* B2p  = (__half*)alloc((size_t)128 * 512 * 2);
  float* ws1 = (float*)alloc(4 * 256 * 4);
  float* wd1 = (float*)alloc(4 * 256 * 4);
  float* ws2 = (float*)alloc(4 * 128 * 4);
  float* wd2 = (float*)alloc(4 * 128 * 4);
  float* as1 = (float*)alloc((size_t)N_NODES * 4 * 4);
  float* ad1 = (float*)alloc((size_t)N_NODES * 4 * 4);
  float* as2 = (float*)alloc((size_t)N_NODES * 4 * 4);
  float* ad2 = (float*)alloc((size_t)N_NODES * 4 * 4);
  int*   row_ptr  = (int*)alloc((size_t)(N_NODES + 1) * 4);  // block-partial
  int*   row_ptrF = (int*)alloc((size_t)(N_NODES + 1) * 4);  // finalized
  int*   deg      = (int*)alloc((size_t)N_NODES * 4);
  int*   bsum     = (int*)alloc((size_t)256 * 4);
  int*   epos     = (int*)alloc((size_t)E_TOT * 4);          // 3.4 MB
  int2*  col2     = (int2*)alloc((size_t)E_TOT * 8);         // 6.8 MB
  float4* wtab    = (float4*)alloc((size_t)E_TOT * 16);      // 13.6 MB

  // lifetime aliases (stream-ordered, no concurrent use):
  //   out1 (12.8 MB)  reuses x16   (x16 dead after aggregate-1)
  //   agg2 (51.4 MB)  reuses agg1  (agg1 dead after gemm_mean-1)
  __half* out1 = x16;
  __half* agg2 = agg1;

  const int edge_blocks = (E_TOT + 255) / 256;
  const int node_wave_blocks = (N_NODES + 3) / 4;   // 12500

  hipMemsetAsync(deg, 0, (size_t)N_NODES * 4, stream);
  prep<<<EB + 208, 256, 0, stream>>>(ei, deg, epos, W1, B1p, W2, B2p,
                                     att_s1, att_d1, att_s2, att_d2,
                                     ws1, wd1, ws2, wd2);
  scan_blocks<<<SBLK, 256, 0, stream>>>(deg, row_ptr, bsum);
  scan_tops<<<1, 256, 0, stream>>>(bsum);
  scatter_pos<<<edge_blocks + SBLK, 256, 0, stream>>>(ei, epos, row_ptr, bsum,
                                                      col2, row_ptrF);

  // layer 1
  prep_x<<<node_wave_blocks, 256, 0, stream>>>(x, ws1, wd1, x16, as1, ad1);
  edge_weights<<<edge_blocks, 256, 0, stream>>>(col2, as1, ad1, wtab);
  gat_aggregate_w<4><<<node_wave_blocks, 256, 0, stream>>>(
      x16, wtab, row_ptrF, col2, agg1);
  gemm_mean<1024, true, true><<<MPAD / 64, 256, 0, stream>>>(
      agg1, B1p, b1, out1, ws2, wd2, as2, ad2);

  // layer 2 (scores already produced by gemm1's fused epilogue)
  edge_weights<<<edge_blocks, 256, 0, stream>>>(col2, as2, ad2, wtab);
  gat_aggregate_w<2><<<node_wave_blocks, 256, 0, stream>>>(
      out1, wtab, row_ptrF, col2, agg2);
  gemm_mean<512, false, false><<<MPAD / 64, 256, 0, stream>>>(
      agg2, B2p, b2, out, nullptr, nullptr, nullptr, nullptr);
}